// Round 1
// baseline (1584.365 us; speedup 1.0000x reference)
//
#include <hip/hip_runtime.h>
#include <hip/hip_bf16.h>
#include <math.h>

// Problem constants (from reference)
#define DM   1024        // d_model
#define DI   2048        // d_inner
#define DS   16          // d_state
#define DTR  64          // dt_rank
#define NB   2           // batch
#define LL   1024        // seq len
#define MR   (NB*LL)     // 2048 rows (b*l flattened)
#define XDBL 96          // dt_rank + 2*d_state

// ---------------------------------------------------------------------------
// LayerNorm: one block per row (m in [0, MR)), 256 threads
// ---------------------------------------------------------------------------
__global__ __launch_bounds__(256) void ln_kernel(
    const float* __restrict__ x, const float* __restrict__ w,
    const float* __restrict__ b, float* __restrict__ h) {
  __shared__ float sA[4], sB[4];
  const int m = blockIdx.x;
  const float* xr = x + (size_t)m * DM;
  float s = 0.f, ss = 0.f;
  for (int i = threadIdx.x; i < DM; i += 256) {
    float v = xr[i];
    s += v; ss += v * v;
  }
  for (int o = 32; o > 0; o >>= 1) {
    s  += __shfl_down(s, o, 64);
    ss += __shfl_down(ss, o, 64);
  }
  const int wid = threadIdx.x >> 6, lid = threadIdx.x & 63;
  if (lid == 0) { sA[wid] = s; sB[wid] = ss; }
  __syncthreads();
  if (threadIdx.x == 0) {
    float S = sA[0] + sA[1] + sA[2] + sA[3];
    float SS = sB[0] + sB[1] + sB[2] + sB[3];
    float mu = S / DM;
    sA[0] = mu;
    sB[0] = rsqrtf(SS / DM - mu * mu + 1e-5f);
  }
  __syncthreads();
  const float mu = sA[0], rs = sB[0];
  for (int i = threadIdx.x; i < DM; i += 256)
    h[(size_t)m * DM + i] = (xr[i] - mu) * rs * w[i] + b[i];
}

// ---------------------------------------------------------------------------
// Generic f32 GEMM:  C[m,n] = sum_k A[m,k] * W[n,k]   (both row-major over k)
// A row stride lda, C row stride ldc. 64x64 tile, BK=16, 4x4 per thread.
// EPI: 0 = none, 1 = softplus(acc + bias[n]), 2 = residual[m*N+n] + acc
// M must be multiple of 64, K multiple of 16; N guarded.
// ---------------------------------------------------------------------------
template <int EPI>
__global__ __launch_bounds__(256) void gemm_atb(
    const float* __restrict__ A, int lda,
    const float* __restrict__ W,
    float* __restrict__ C, int ldc,
    const float* __restrict__ extra,
    int M, int N, int K) {
  __shared__ float As[16][68];   // +4 pad: keeps rows 16B aligned, spreads banks
  __shared__ float Ws[16][68];
  const int t = threadIdx.x;
  const int m0 = blockIdx.y * 64, n0 = blockIdx.x * 64;
  const int tm = t >> 4, tn = t & 15;
  const int lr = t >> 4, lc = t & 15;
  float acc[4][4] = {};
  for (int k0 = 0; k0 < K; k0 += 16) {
#pragma unroll
    for (int i = 0; i < 4; i++) {
      int r = lr + i * 16;
      As[lc][r] = A[(size_t)(m0 + r) * lda + k0 + lc];
      int nn = n0 + r;
      Ws[lc][r] = (nn < N) ? W[(size_t)nn * K + k0 + lc] : 0.f;
    }
    __syncthreads();
#pragma unroll
    for (int kk = 0; kk < 16; kk++) {
      float a[4], w[4];
#pragma unroll
      for (int i = 0; i < 4; i++) a[i] = As[kk][tm * 4 + i];
#pragma unroll
      for (int j = 0; j < 4; j++) w[j] = Ws[kk][tn * 4 + j];
#pragma unroll
      for (int i = 0; i < 4; i++)
#pragma unroll
        for (int j = 0; j < 4; j++) acc[i][j] += a[i] * w[j];
    }
    __syncthreads();
  }
#pragma unroll
  for (int i = 0; i < 4; i++) {
    int mm = m0 + tm * 4 + i;
#pragma unroll
    for (int j = 0; j < 4; j++) {
      int nn = n0 + tn * 4 + j;
      if (nn < N) {
        float v = acc[i][j];
        if (EPI == 1) {
          v += extra[nn];
          v = (v > 20.f) ? v : log1pf(expf(v));   // softplus
        } else if (EPI == 2) {
          v += extra[(size_t)mm * N + nn];        // residual
        }
        C[(size_t)mm * ldc + nn] = v;
      }
    }
  }
}

// ---------------------------------------------------------------------------
// Depthwise causal conv1d (width 4) + bias + SiLU.
// x_in = xz[:, :, 0:DI] (row stride 2*DI). One thread per (m, d).
// ---------------------------------------------------------------------------
__global__ __launch_bounds__(256) void conv_silu_kernel(
    const float* __restrict__ xz, const float* __restrict__ cw,
    const float* __restrict__ cb, float* __restrict__ xc) {
  const int idx = blockIdx.x * 256 + threadIdx.x;   // 0 .. MR*DI-1
  const int d  = idx & (DI - 1);
  const int ml = idx >> 11;                          // m = b*LL + l
  const int l  = ml & (LL - 1);
  float acc = cb[d];
#pragma unroll
  for (int k = 0; k < 4; k++) {
    int lp = l - 3 + k;
    if (lp >= 0)
      acc += xz[(size_t)(ml - (3 - k)) * (2 * DI) + d] * cw[d * 4 + k];
  }
  xc[idx] = acc / (1.f + expf(-acc));                // silu
}

// ---------------------------------------------------------------------------
// Selective scan. One thread per (b, d, s). 16 d-channels per 256-thread block.
// Butterfly shfl_xor over the 16 states to form y[m,d] = sum_s h*C, then
// fused + u*D and * silu(z). y written into the (dead) x_in half of xz.
// ---------------------------------------------------------------------------
__global__ __launch_bounds__(256) void scan_kernel(
    const float* __restrict__ xc,    // x_conv (MR x DI)
    const float* __restrict__ xdbl,  // (MR x 96): [dt(64) | B(16) | C(16)]
    const float* __restrict__ dtm,   // dt after softplus (MR x DI)
    const float* __restrict__ xz,    // for z = xz[:, DI:2*DI]
    float* __restrict__ y,           // output, row stride 2*DI (aliases xz x_in)
    const float* __restrict__ A_log, const float* __restrict__ Dvec) {
  const int blk = blockIdx.x;          // 0..255
  const int b = blk >> 7;              // 128 d-blocks per batch
  const int dblk = blk & 127;
  const int t = threadIdx.x;
  const int s = t & 15, dloc = t >> 4;
  const int d = dblk * 16 + dloc;
  const float a = -expf(A_log[d * DS + s]);
  const float Dv = Dvec[d];
  float hst = 0.f;
  const size_t baseML = (size_t)b * LL;
  for (int l = 0; l < LL; l++) {
    const size_t ml = baseML + l;
    const float dtv = dtm[ml * DI + d];
    const float u   = xc[ml * DI + d];
    const float Bv  = xdbl[ml * XDBL + DTR + s];
    const float Cv  = xdbl[ml * XDBL + DTR + DS + s];
    hst = expf(dtv * a) * hst + dtv * Bv * u;
    float p = hst * Cv;
    p += __shfl_xor(p, 1, 16);
    p += __shfl_xor(p, 2, 16);
    p += __shfl_xor(p, 4, 16);
    p += __shfl_xor(p, 8, 16);
    if (s == 0) {
      const float zv = xz[ml * (2 * DI) + DI + d];
      const float sil = zv / (1.f + expf(-zv));
      y[ml * (2 * DI) + d] = (p + u * Dv) * sil;
    }
  }
}

// ---------------------------------------------------------------------------
// Launch
// ---------------------------------------------------------------------------
extern "C" void kernel_launch(void* const* d_in, const int* in_sizes, int n_in,
                              void* d_out, int out_size, void* d_ws, size_t ws_size,
                              hipStream_t stream) {
  const float* x         = (const float*)d_in[0];
  const float* ln_w      = (const float*)d_in[1];
  const float* ln_b      = (const float*)d_in[2];
  const float* in_proj_w = (const float*)d_in[3];   // (4096, 1024)
  const float* conv_w    = (const float*)d_in[4];   // (2048, 1, 4)
  const float* conv_b    = (const float*)d_in[5];
  const float* x_proj_w  = (const float*)d_in[6];   // (96, 2048)
  const float* dt_proj_w = (const float*)d_in[7];   // (2048, 64)
  const float* dt_proj_b = (const float*)d_in[8];
  const float* A_log     = (const float*)d_in[9];   // (2048, 16)
  const float* Dvec      = (const float*)d_in[10];
  const float* out_proj_w= (const float*)d_in[11];  // (1024, 2048)
  float* out = (float*)d_out;

  // workspace layout (floats)
  float* ws = (float*)d_ws;
  float* h      = ws;                                   // MR*DM     = 2,097,152
  float* xz     = h + (size_t)MR * DM;                  // MR*2*DI   = 8,388,608
  float* x_conv = xz + (size_t)MR * 2 * DI;             // MR*DI     = 4,194,304
  float* x_dbl  = x_conv + (size_t)MR * DI;             // MR*96     =   196,608
  float* dtb    = x_dbl + (size_t)MR * XDBL;            // MR*DI     = 4,194,304
  float* y      = xz;                                   // aliases x_in half (dead after conv)

  // 1. layernorm
  ln_kernel<<<MR, 256, 0, stream>>>(x, ln_w, ln_b, h);

  // 2. in_proj: xz = h @ in_proj_w^T   (M=2048, N=4096, K=1024)
  gemm_atb<0><<<dim3(4096 / 64, MR / 64), 256, 0, stream>>>(
      h, DM, in_proj_w, xz, 2 * DI, nullptr, MR, 2 * DI, DM);

  // 3. conv + silu -> x_conv
  conv_silu_kernel<<<(MR * DI) / 256, 256, 0, stream>>>(xz, conv_w, conv_b, x_conv);

  // 4. x_proj: x_dbl = x_conv @ x_proj_w^T   (M=2048, N=96, K=2048)
  gemm_atb<0><<<dim3(2, MR / 64), 256, 0, stream>>>(
      x_conv, DI, x_proj_w, x_dbl, XDBL, nullptr, MR, XDBL, DI);

  // 5. dt: dtb = softplus(x_dbl[:, :64] @ dt_proj_w^T + dt_proj_b)  (M=2048, N=2048, K=64)
  gemm_atb<1><<<dim3(DI / 64, MR / 64), 256, 0, stream>>>(
      x_dbl, XDBL, dt_proj_w, dtb, DI, dt_proj_b, MR, DI, DTR);

  // 6. selective scan -> y (row stride 2*DI, in xz's x_in half)
  scan_kernel<<<NB * (DI / 16), 256, 0, stream>>>(
      x_conv, x_dbl, dtb, xz, y, A_log, Dvec);

  // 7. out_proj + residual: out = x + y @ out_proj_w^T  (M=2048, N=1024, K=2048)
  gemm_atb<2><<<dim3(DM / 64, MR / 64), 256, 0, stream>>>(
      y, 2 * DI, out_proj_w, out, DM, x, MR, DM, DI);
}

// Round 2
// 851.667 us; speedup vs baseline: 1.8603x; 1.8603x over previous
//
#include <hip/hip_runtime.h>
#include <hip/hip_bf16.h>
#include <math.h>

// Problem constants (from reference)
#define DM   1024        // d_model
#define DI   2048        // d_inner
#define DS   16          // d_state
#define DTR  64          // dt_rank
#define NB   2           // batch
#define LL   1024        // seq len
#define MR   (NB*LL)     // 2048 rows (b*l flattened)
#define XDBL 96          // dt_rank + 2*d_state
#define NC   32          // scan chunks
#define CL   32          // chunk length (NC*CL == LL)

// ---------------------------------------------------------------------------
// LayerNorm: one block per row (m in [0, MR)), 256 threads
// ---------------------------------------------------------------------------
__global__ __launch_bounds__(256) void ln_kernel(
    const float* __restrict__ x, const float* __restrict__ w,
    const float* __restrict__ b, float* __restrict__ h) {
  __shared__ float sA[4], sB[4];
  const int m = blockIdx.x;
  const float* xr = x + (size_t)m * DM;
  float s = 0.f, ss = 0.f;
  for (int i = threadIdx.x; i < DM; i += 256) {
    float v = xr[i];
    s += v; ss += v * v;
  }
  for (int o = 32; o > 0; o >>= 1) {
    s  += __shfl_down(s, o, 64);
    ss += __shfl_down(ss, o, 64);
  }
  const int wid = threadIdx.x >> 6, lid = threadIdx.x & 63;
  if (lid == 0) { sA[wid] = s; sB[wid] = ss; }
  __syncthreads();
  if (threadIdx.x == 0) {
    float S = sA[0] + sA[1] + sA[2] + sA[3];
    float SS = sB[0] + sB[1] + sB[2] + sB[3];
    float mu = S / DM;
    sA[0] = mu;
    sB[0] = rsqrtf(SS / DM - mu * mu + 1e-5f);
  }
  __syncthreads();
  const float mu = sA[0], rs = sB[0];
  for (int i = threadIdx.x; i < DM; i += 256)
    h[(size_t)m * DM + i] = (xr[i] - mu) * rs * w[i] + b[i];
}

// ---------------------------------------------------------------------------
// Generic f32 GEMM:  C[m,n] = sum_k A[m,k] * W[n,k]   (both row-major over k)
// A row stride lda, C row stride ldc. 64x64 tile, BK=16, 4x4 per thread.
// EPI: 0 = none, 1 = softplus(acc + bias[n]), 2 = residual[m*N+n] + acc
// M must be multiple of 64, K multiple of 16; N guarded.
// ---------------------------------------------------------------------------
template <int EPI>
__global__ __launch_bounds__(256) void gemm_atb(
    const float* __restrict__ A, int lda,
    const float* __restrict__ W,
    float* __restrict__ C, int ldc,
    const float* __restrict__ extra,
    int M, int N, int K) {
  __shared__ float As[16][68];   // +4 pad: keeps rows 16B aligned, spreads banks
  __shared__ float Ws[16][68];
  const int t = threadIdx.x;
  const int m0 = blockIdx.y * 64, n0 = blockIdx.x * 64;
  const int tm = t >> 4, tn = t & 15;
  const int lr = t >> 4, lc = t & 15;
  float acc[4][4] = {};
  for (int k0 = 0; k0 < K; k0 += 16) {
#pragma unroll
    for (int i = 0; i < 4; i++) {
      int r = lr + i * 16;
      As[lc][r] = A[(size_t)(m0 + r) * lda + k0 + lc];
      int nn = n0 + r;
      Ws[lc][r] = (nn < N) ? W[(size_t)nn * K + k0 + lc] : 0.f;
    }
    __syncthreads();
#pragma unroll
    for (int kk = 0; kk < 16; kk++) {
      float a[4], w[4];
#pragma unroll
      for (int i = 0; i < 4; i++) a[i] = As[kk][tm * 4 + i];
#pragma unroll
      for (int j = 0; j < 4; j++) w[j] = Ws[kk][tn * 4 + j];
#pragma unroll
      for (int i = 0; i < 4; i++)
#pragma unroll
        for (int j = 0; j < 4; j++) acc[i][j] += a[i] * w[j];
    }
    __syncthreads();
  }
#pragma unroll
  for (int i = 0; i < 4; i++) {
    int mm = m0 + tm * 4 + i;
#pragma unroll
    for (int j = 0; j < 4; j++) {
      int nn = n0 + tn * 4 + j;
      if (nn < N) {
        float v = acc[i][j];
        if (EPI == 1) {
          v += extra[nn];
          v = (v > 20.f) ? v : log1pf(expf(v));   // softplus
        } else if (EPI == 2) {
          v += extra[(size_t)mm * N + nn];        // residual
        }
        C[(size_t)mm * ldc + nn] = v;
      }
    }
  }
}

// ---------------------------------------------------------------------------
// Depthwise causal conv1d (width 4) + bias + SiLU.
// x_in = xz[:, :, 0:DI] (row stride 2*DI). One thread per (m, d).
// ---------------------------------------------------------------------------
__global__ __launch_bounds__(256) void conv_silu_kernel(
    const float* __restrict__ xz, const float* __restrict__ cw,
    const float* __restrict__ cb, float* __restrict__ xc) {
  const int idx = blockIdx.x * 256 + threadIdx.x;   // 0 .. MR*DI-1
  const int d  = idx & (DI - 1);
  const int ml = idx >> 11;                          // m = b*LL + l
  const int l  = ml & (LL - 1);
  float acc = cb[d];
#pragma unroll
  for (int k = 0; k < 4; k++) {
    int lp = l - 3 + k;
    if (lp >= 0)
      acc += xz[(size_t)(ml - (3 - k)) * (2 * DI) + d] * cw[d * 4 + k];
  }
  xc[idx] = acc / (1.f + __expf(-acc));              // silu
}

// ---------------------------------------------------------------------------
// Chunked selective scan, phase 1: per-(b,chunk) local scan with h=0 init.
// Thread = one d channel (coalesced), 16 states in registers (16-way ILP).
// Emits chunk-local end state h_end[(b*NC+c)*DS+s][d] and S = sum(dt) per d.
// ---------------------------------------------------------------------------
__global__ __launch_bounds__(256) void scan_phase1(
    const float* __restrict__ xc,    // x_conv (MR x DI)
    const float* __restrict__ xdbl,  // (MR x 96): [dt(64) | B(16) | C(16)]
    const float* __restrict__ dtm,   // dt after softplus (MR x DI)
    const float* __restrict__ A_log,
    float* __restrict__ HE,          // (NB*NC*DS) x DI  chunk-end local states
    float* __restrict__ SA) {        // (NB*NC) x DI     sum of dt over chunk
  __shared__ float Bs[CL][DS];
  const int bi = blockIdx.x;                 // NB*NC*(DI/256)
  const int dblk = bi & 7;                   // DI/256 = 8
  const int c = (bi >> 3) & (NC - 1);
  const int b = bi >> 8;                     // / (8*NC)
  const int t = threadIdx.x;
  const int d = dblk * 256 + t;
  const int mlbase = b * LL + c * CL;

  // cooperative load of B for the chunk: CL*DS = 512 floats
  for (int i = t; i < CL * DS; i += 256) {
    int tt = i >> 4, s = i & 15;
    Bs[tt][s] = xdbl[(size_t)(mlbase + tt) * XDBL + DTR + s];
  }

  float a[DS];
  const float4* Ap = (const float4*)(A_log + (size_t)d * DS);
#pragma unroll
  for (int i = 0; i < 4; i++) {
    float4 v = Ap[i];
    a[4 * i + 0] = -__expf(v.x); a[4 * i + 1] = -__expf(v.y);
    a[4 * i + 2] = -__expf(v.z); a[4 * i + 3] = -__expf(v.w);
  }
  float h[DS];
#pragma unroll
  for (int s = 0; s < DS; s++) h[s] = 0.f;
  float S = 0.f;
  __syncthreads();

  for (int tt = 0; tt < CL; tt++) {
    const size_t ml = mlbase + tt;
    const float dtv = dtm[ml * DI + d];
    const float u   = xc[ml * DI + d];
    const float du  = dtv * u;
    S += dtv;
#pragma unroll
    for (int s = 0; s < DS; s++)
      h[s] = __expf(dtv * a[s]) * h[s] + du * Bs[tt][s];
  }
  const size_t base = ((size_t)(b * NC + c) * DS) * DI + d;
#pragma unroll
  for (int s = 0; s < DS; s++) HE[base + (size_t)s * DI] = h[s];
  SA[(size_t)(b * NC + c) * DI + d] = S;
}

// ---------------------------------------------------------------------------
// Phase 2: sequential combine over chunks. One thread per (b,d,s).
// In-place: HE[c] becomes the carry-IN state for chunk c.
// Chunk decay product = exp(a * sum(dt)) since prod(exp(a*dt)) = exp(a*S).
// ---------------------------------------------------------------------------
__global__ __launch_bounds__(256) void scan_phase2(
    const float* __restrict__ A_log,
    const float* __restrict__ SA,
    float* __restrict__ HE) {
  const int idx = blockIdx.x * 256 + threadIdx.x;  // NB*DS*DI
  const int d = idx & (DI - 1);
  const int s = (idx >> 11) & (DS - 1);
  const int b = idx >> 15;
  const float a = -__expf(A_log[(size_t)d * DS + s]);
  float Hc = 0.f;
  for (int c = 0; c < NC; c++) {
    const size_t o = ((size_t)(b * NC + c) * DS + s) * DI + d;
    const float he = HE[o];
    const float P = __expf(a * SA[(size_t)(b * NC + c) * DI + d]);
    HE[o] = Hc;                 // carry-in for chunk c
    Hc = P * Hc + he;
  }
}

// ---------------------------------------------------------------------------
// Phase 3: re-run each chunk with correct carry-in; fuse y = sum_s h*C + u*D,
// then * silu(z). y written into the (dead) x_in half of xz.
// ---------------------------------------------------------------------------
__global__ __launch_bounds__(256) void scan_phase3(
    const float* __restrict__ xc,
    const float* __restrict__ xdbl,
    const float* __restrict__ dtm,
    const float* __restrict__ xz,    // z = xz[:, DI:2*DI]
    const float* __restrict__ A_log,
    const float* __restrict__ Dvec,
    const float* __restrict__ HE,    // carry-in states from phase 2
    float* __restrict__ y) {         // row stride 2*DI (aliases xz x_in half)
  __shared__ float Bs[CL][DS];
  __shared__ float Cs[CL][DS];
  const int bi = blockIdx.x;
  const int dblk = bi & 7;
  const int c = (bi >> 3) & (NC - 1);
  const int b = bi >> 8;
  const int t = threadIdx.x;
  const int d = dblk * 256 + t;
  const int mlbase = b * LL + c * CL;

  for (int i = t; i < CL * DS; i += 256) {
    int tt = i >> 4, s = i & 15;
    const size_t ro = (size_t)(mlbase + tt) * XDBL + DTR + s;
    Bs[tt][s] = xdbl[ro];
    Cs[tt][s] = xdbl[ro + DS];
  }

  float a[DS];
  const float4* Ap = (const float4*)(A_log + (size_t)d * DS);
#pragma unroll
  for (int i = 0; i < 4; i++) {
    float4 v = Ap[i];
    a[4 * i + 0] = -__expf(v.x); a[4 * i + 1] = -__expf(v.y);
    a[4 * i + 2] = -__expf(v.z); a[4 * i + 3] = -__expf(v.w);
  }
  float h[DS];
  const size_t base = ((size_t)(b * NC + c) * DS) * DI + d;
#pragma unroll
  for (int s = 0; s < DS; s++) h[s] = HE[base + (size_t)s * DI];
  const float Dv = Dvec[d];
  __syncthreads();

  for (int tt = 0; tt < CL; tt++) {
    const size_t ml = mlbase + tt;
    const float dtv = dtm[ml * DI + d];
    const float u   = xc[ml * DI + d];
    const float du  = dtv * u;
    float p = 0.f;
#pragma unroll
    for (int s = 0; s < DS; s++) {
      h[s] = __expf(dtv * a[s]) * h[s] + du * Bs[tt][s];
      p += h[s] * Cs[tt][s];
    }
    const float zv = xz[ml * (2 * DI) + DI + d];
    const float sil = zv / (1.f + __expf(-zv));
    y[ml * (2 * DI) + d] = (p + u * Dv) * sil;
  }
}

// ---------------------------------------------------------------------------
// Launch
// ---------------------------------------------------------------------------
extern "C" void kernel_launch(void* const* d_in, const int* in_sizes, int n_in,
                              void* d_out, int out_size, void* d_ws, size_t ws_size,
                              hipStream_t stream) {
  const float* x         = (const float*)d_in[0];
  const float* ln_w      = (const float*)d_in[1];
  const float* ln_b      = (const float*)d_in[2];
  const float* in_proj_w = (const float*)d_in[3];   // (4096, 1024)
  const float* conv_w    = (const float*)d_in[4];   // (2048, 1, 4)
  const float* conv_b    = (const float*)d_in[5];
  const float* x_proj_w  = (const float*)d_in[6];   // (96, 2048)
  const float* dt_proj_w = (const float*)d_in[7];   // (2048, 64)
  const float* dt_proj_b = (const float*)d_in[8];
  const float* A_log     = (const float*)d_in[9];   // (2048, 16)
  const float* Dvec      = (const float*)d_in[10];
  const float* out_proj_w= (const float*)d_in[11];  // (1024, 2048)
  float* out = (float*)d_out;

  // workspace layout (floats)
  float* ws = (float*)d_ws;
  float* h      = ws;                                   // MR*DM     = 2,097,152
  float* xz     = h + (size_t)MR * DM;                  // MR*2*DI   = 8,388,608
  float* x_conv = xz + (size_t)MR * 2 * DI;             // MR*DI     = 4,194,304
  float* x_dbl  = x_conv + (size_t)MR * DI;             // MR*96     =   196,608
  float* dtb    = x_dbl + (size_t)MR * XDBL;            // MR*DI     = 4,194,304
  float* SA     = dtb + (size_t)MR * DI;                // NB*NC*DI  =   131,072
  float* HE     = h;        // NB*NC*DS*DI = 2,097,152 — aliases h (dead after in_proj)
  float* y      = xz;       // aliases x_in half (dead after conv)

  // 1. layernorm
  ln_kernel<<<MR, 256, 0, stream>>>(x, ln_w, ln_b, h);

  // 2. in_proj: xz = h @ in_proj_w^T   (M=2048, N=4096, K=1024)
  gemm_atb<0><<<dim3(4096 / 64, MR / 64), 256, 0, stream>>>(
      h, DM, in_proj_w, xz, 2 * DI, nullptr, MR, 2 * DI, DM);

  // 3. conv + silu -> x_conv
  conv_silu_kernel<<<(MR * DI) / 256, 256, 0, stream>>>(xz, conv_w, conv_b, x_conv);

  // 4. x_proj: x_dbl = x_conv @ x_proj_w^T   (M=2048, N=96, K=2048)
  gemm_atb<0><<<dim3(2, MR / 64), 256, 0, stream>>>(
      x_conv, DI, x_proj_w, x_dbl, XDBL, nullptr, MR, XDBL, DI);

  // 5. dt: dtb = softplus(x_dbl[:, :64] @ dt_proj_w^T + dt_proj_b)  (M=2048, N=2048, K=64)
  gemm_atb<1><<<dim3(DI / 64, MR / 64), 256, 0, stream>>>(
      x_dbl, XDBL, dt_proj_w, dtb, DI, dt_proj_b, MR, DI, DTR);

  // 6. chunked selective scan (h is dead after step 2 -> reused as HE)
  scan_phase1<<<NB * NC * (DI / 256), 256, 0, stream>>>(
      x_conv, x_dbl, dtb, A_log, HE, SA);
  scan_phase2<<<(NB * DS * DI) / 256, 256, 0, stream>>>(A_log, SA, HE);
  scan_phase3<<<NB * NC * (DI / 256), 256, 0, stream>>>(
      x_conv, x_dbl, dtb, xz, A_log, Dvec, HE, y);

  // 7. out_proj + residual: out = x + y @ out_proj_w^T  (M=2048, N=1024, K=2048)
  gemm_atb<2><<<dim3(DM / 64, MR / 64), 256, 0, stream>>>(
      y, 2 * DI, out_proj_w, out, DM, x, MR, DM, DI);
}

// Round 3
// 330.103 us; speedup vs baseline: 4.7996x; 2.5800x over previous
//
#include <hip/hip_runtime.h>
#include <hip/hip_bf16.h>
#include <math.h>

// Problem constants (from reference)
#define DM   1024        // d_model
#define DI   2048        // d_inner
#define DS   16          // d_state
#define DTR  64          // dt_rank
#define NB   2           // batch
#define LL   1024        // seq len
#define MR   (NB*LL)     // 2048 rows (b*l flattened)
#define XDBL 96          // dt_rank + 2*d_state
#define NC   32          // scan chunks
#define CL   32          // chunk length (NC*CL == LL)

typedef _Float16 half8  __attribute__((ext_vector_type(8)));
typedef _Float16 half4v __attribute__((ext_vector_type(4)));
typedef float    floatx4 __attribute__((ext_vector_type(4)));

__device__ __forceinline__ void gload_lds16(const void* g, void* l) {
  __builtin_amdgcn_global_load_lds(
      (const __attribute__((address_space(1))) void*)g,
      (__attribute__((address_space(3))) void*)l, 16, 0, 0);
}

// ---------------------------------------------------------------------------
// f32 -> f16 conversion (n multiple of 4)
// ---------------------------------------------------------------------------
__global__ __launch_bounds__(256) void f2h_kernel(
    const float* __restrict__ s, _Float16* __restrict__ d, int n4) {
  int i = blockIdx.x * 256 + threadIdx.x;
  if (i < n4) {
    float4 v = ((const float4*)s)[i];
    half4v h = {(_Float16)v.x, (_Float16)v.y, (_Float16)v.z, (_Float16)v.w};
    ((half4v*)d)[i] = h;
  }
}

__global__ __launch_bounds__(256) void zero_kernel(float* __restrict__ p, int n4) {
  int i = blockIdx.x * 256 + threadIdx.x;
  if (i < n4) ((float4*)p)[i] = make_float4(0.f, 0.f, 0.f, 0.f);
}

// x_dbl[:, 0:64] f32 -> compact f16 [MR][64]
__global__ __launch_bounds__(256) void dtext_kernel(
    const float* __restrict__ xdbl, _Float16* __restrict__ dtr) {
  int idx = blockIdx.x * 256 + threadIdx.x;   // MR*DTR
  int m = idx >> 6, c = idx & 63;
  dtr[idx] = (_Float16)xdbl[(size_t)m * XDBL + c];
}

// ---------------------------------------------------------------------------
// LayerNorm -> f16 output
// ---------------------------------------------------------------------------
__global__ __launch_bounds__(256) void ln_kernel(
    const float* __restrict__ x, const float* __restrict__ w,
    const float* __restrict__ b, _Float16* __restrict__ h) {
  __shared__ float sA[4], sB[4];
  const int m = blockIdx.x;
  const float* xr = x + (size_t)m * DM;
  float s = 0.f, ss = 0.f;
  for (int i = threadIdx.x; i < DM; i += 256) {
    float v = xr[i];
    s += v; ss += v * v;
  }
  for (int o = 32; o > 0; o >>= 1) {
    s  += __shfl_down(s, o, 64);
    ss += __shfl_down(ss, o, 64);
  }
  const int wid = threadIdx.x >> 6, lid = threadIdx.x & 63;
  if (lid == 0) { sA[wid] = s; sB[wid] = ss; }
  __syncthreads();
  if (threadIdx.x == 0) {
    float S = sA[0] + sA[1] + sA[2] + sA[3];
    float SS = sB[0] + sB[1] + sB[2] + sB[3];
    float mu = S / DM;
    sA[0] = mu;
    sB[0] = rsqrtf(SS / DM - mu * mu + 1e-5f);
  }
  __syncthreads();
  const float mu = sA[0], rs = sB[0];
  for (int i = threadIdx.x; i < DM; i += 256)
    h[(size_t)m * DM + i] = (_Float16)((xr[i] - mu) * rs * w[i] + b[i]);
}

// ---------------------------------------------------------------------------
// MFMA f16 GEMM: C[m,n] = sum_k A[m,k]*W[n,k], fp32 accumulate.
// 128x128 tile, BK=32, 4 waves each computing 64x64 (4x4 tiles of 16x16x32).
// global_load_lds width-16 staging (LDS layout = lane-linear, no padding).
// EPI: 0 = store; 1 = softplus(acc+bias[n]); 2 = residual[m*N+n]+acc;
//      3 = atomicAdd (split-K over blockIdx.z, C pre-zeroed).
// M multiple of 128; N guarded (W row reads clamped).
// ---------------------------------------------------------------------------
template <int EPI>
__global__ __launch_bounds__(256) void gemm_mfma(
    const _Float16* __restrict__ A,   // [M][K]
    const _Float16* __restrict__ W,   // [N][K]
    float* __restrict__ C, int ldc,
    const float* __restrict__ extra,
    int M, int N, int K, int kchunk) {
  __shared__ alignas(16) _Float16 As[128 * 32];
  __shared__ alignas(16) _Float16 Ws[128 * 32];
  const int t = threadIdx.x;
  const int wave = t >> 6, lane = t & 63;
  const int m0 = blockIdx.y * 128, n0 = blockIdx.x * 128;
  const int k_beg = blockIdx.z * kchunk;
  const int k_end = min(K, k_beg + kchunk);
  const int wm = (wave >> 1) * 64, wn = (wave & 1) * 64;
  floatx4 acc[4][4];
#pragma unroll
  for (int i = 0; i < 4; i++)
#pragma unroll
    for (int j = 0; j < 4; j++) acc[i][j] = {0.f, 0.f, 0.f, 0.f};

  const int fr = lane & 15;     // row within 16-tile
  const int kc8 = lane >> 4;    // which 8-half k-chunk

  for (int k0 = k_beg; k0 < k_end; k0 += 32) {
#pragma unroll
    for (int j = 0; j < 2; j++) {
      const int slot = (j * 4 + wave) * 64 + lane;
      const int row = slot >> 2, kc = slot & 3;
      const int wrow = (row < N) ? row : 0;   // clamp W reads when N<128
      gload_lds16(A + (size_t)(m0 + row) * K + k0 + kc * 8,
                  &As[(j * 4 + wave) * 512]);
      gload_lds16(W + (size_t)(n0 + wrow) * K + k0 + kc * 8,
                  &Ws[(j * 4 + wave) * 512]);
    }
    __syncthreads();
    half8 af[4], wf[4];
#pragma unroll
    for (int i = 0; i < 4; i++) {
      af[i] = *(const half8*)&As[(wm + i * 16 + fr) * 32 + kc8 * 8];
      wf[i] = *(const half8*)&Ws[(wn + i * 16 + fr) * 32 + kc8 * 8];
    }
#pragma unroll
    for (int i = 0; i < 4; i++)
#pragma unroll
      for (int j = 0; j < 4; j++)
        acc[i][j] = __builtin_amdgcn_mfma_f32_16x16x32_f16(af[i], wf[j], acc[i][j], 0, 0, 0);
    __syncthreads();
  }

  // epilogue: C/D layout col = lane&15, row = (lane>>4)*4 + reg
  const int col = lane & 15, rowq = lane >> 4;
#pragma unroll
  for (int i = 0; i < 4; i++) {
#pragma unroll
    for (int j = 0; j < 4; j++) {
      const int n = n0 + wn + j * 16 + col;
      if (n < N) {
#pragma unroll
        for (int r = 0; r < 4; r++) {
          const int m = m0 + wm + i * 16 + rowq * 4 + r;
          float v = acc[i][j][r];
          if (EPI == 1) {
            v += extra[n];
            v = (v > 20.f) ? v : log1pf(expf(v));   // softplus
          } else if (EPI == 2) {
            v += extra[(size_t)m * N + n];          // residual
          }
          if (EPI == 3) atomicAdd(&C[(size_t)m * ldc + n], v);
          else          C[(size_t)m * ldc + n] = v;
        }
      }
    }
  }
}

// ---------------------------------------------------------------------------
// Depthwise causal conv1d (width 4) + bias + SiLU. Reads compact x_in f32,
// writes f16 x_conv.
// ---------------------------------------------------------------------------
__global__ __launch_bounds__(256) void conv_silu_kernel(
    const float* __restrict__ xin, const float* __restrict__ cw,
    const float* __restrict__ cb, _Float16* __restrict__ xc) {
  const int idx = blockIdx.x * 256 + threadIdx.x;   // 0 .. MR*DI-1
  const int d  = idx & (DI - 1);
  const int ml = idx >> 11;
  const int l  = ml & (LL - 1);
  float acc = cb[d];
#pragma unroll
  for (int k = 0; k < 4; k++) {
    int lp = l - 3 + k;
    if (lp >= 0)
      acc += xin[(size_t)(ml - (3 - k)) * DI + d] * cw[d * 4 + k];
  }
  xc[idx] = (_Float16)(acc / (1.f + __expf(-acc)));
}

// ---------------------------------------------------------------------------
// Chunked selective scan, phase 1: per-(b,chunk) local scan with h=0 init.
// ---------------------------------------------------------------------------
__global__ __launch_bounds__(256) void scan_phase1(
    const _Float16* __restrict__ xc,  // x_conv (MR x DI) f16
    const float* __restrict__ xdbl,   // (MR x 96)
    const float* __restrict__ dtm,    // dt after softplus (MR x DI)
    const float* __restrict__ A_log,
    float* __restrict__ HE,           // (NB*NC*DS) x DI
    float* __restrict__ SA) {         // (NB*NC) x DI
  __shared__ float Bs[CL][DS];
  const int bi = blockIdx.x;
  const int dblk = bi & 7;
  const int c = (bi >> 3) & (NC - 1);
  const int b = bi >> 8;
  const int t = threadIdx.x;
  const int d = dblk * 256 + t;
  const int mlbase = b * LL + c * CL;

  for (int i = t; i < CL * DS; i += 256) {
    int tt = i >> 4, s = i & 15;
    Bs[tt][s] = xdbl[(size_t)(mlbase + tt) * XDBL + DTR + s];
  }

  float a[DS];
  const float4* Ap = (const float4*)(A_log + (size_t)d * DS);
#pragma unroll
  for (int i = 0; i < 4; i++) {
    float4 v = Ap[i];
    a[4 * i + 0] = -__expf(v.x); a[4 * i + 1] = -__expf(v.y);
    a[4 * i + 2] = -__expf(v.z); a[4 * i + 3] = -__expf(v.w);
  }
  float h[DS];
#pragma unroll
  for (int s = 0; s < DS; s++) h[s] = 0.f;
  float S = 0.f;
  __syncthreads();

  for (int tt = 0; tt < CL; tt++) {
    const size_t ml = mlbase + tt;
    const float dtv = dtm[ml * DI + d];
    const float u   = (float)xc[ml * DI + d];
    const float du  = dtv * u;
    S += dtv;
#pragma unroll
    for (int s = 0; s < DS; s++)
      h[s] = __expf(dtv * a[s]) * h[s] + du * Bs[tt][s];
  }
  const size_t base = ((size_t)(b * NC + c) * DS) * DI + d;
#pragma unroll
  for (int s = 0; s < DS; s++) HE[base + (size_t)s * DI] = h[s];
  SA[(size_t)(b * NC + c) * DI + d] = S;
}

// ---------------------------------------------------------------------------
// Phase 2: sequential combine over chunk aggregates; HE becomes carry-in.
// ---------------------------------------------------------------------------
__global__ __launch_bounds__(256) void scan_phase2(
    const float* __restrict__ A_log,
    const float* __restrict__ SA,
    float* __restrict__ HE) {
  const int idx = blockIdx.x * 256 + threadIdx.x;  // NB*DS*DI
  const int d = idx & (DI - 1);
  const int s = (idx >> 11) & (DS - 1);
  const int b = idx >> 15;
  const float a = -__expf(A_log[(size_t)d * DS + s]);
  float Hc = 0.f;
  for (int c = 0; c < NC; c++) {
    const size_t o = ((size_t)(b * NC + c) * DS + s) * DI + d;
    const float he = HE[o];
    const float P = __expf(a * SA[(size_t)(b * NC + c) * DI + d]);
    HE[o] = Hc;
    Hc = P * Hc + he;
  }
}

// ---------------------------------------------------------------------------
// Phase 3: re-run chunks with carry-in; fuse y = (sum_s h*C + u*D)*silu(z).
// Writes compact f16 y.
// ---------------------------------------------------------------------------
__global__ __launch_bounds__(256) void scan_phase3(
    const _Float16* __restrict__ xc,
    const float* __restrict__ xdbl,
    const float* __restrict__ dtm,
    const float* __restrict__ zbuf,   // z (MR x DI) f32
    const float* __restrict__ A_log,
    const float* __restrict__ Dvec,
    const float* __restrict__ HE,
    _Float16* __restrict__ y) {       // (MR x DI) f16
  __shared__ float Bs[CL][DS];
  __shared__ float Cs[CL][DS];
  const int bi = blockIdx.x;
  const int dblk = bi & 7;
  const int c = (bi >> 3) & (NC - 1);
  const int b = bi >> 8;
  const int t = threadIdx.x;
  const int d = dblk * 256 + t;
  const int mlbase = b * LL + c * CL;

  for (int i = t; i < CL * DS; i += 256) {
    int tt = i >> 4, s = i & 15;
    const size_t ro = (size_t)(mlbase + tt) * XDBL + DTR + s;
    Bs[tt][s] = xdbl[ro];
    Cs[tt][s] = xdbl[ro + DS];
  }

  float a[DS];
  const float4* Ap = (const float4*)(A_log + (size_t)d * DS);
#pragma unroll
  for (int i = 0; i < 4; i++) {
    float4 v = Ap[i];
    a[4 * i + 0] = -__expf(v.x); a[4 * i + 1] = -__expf(v.y);
    a[4 * i + 2] = -__expf(v.z); a[4 * i + 3] = -__expf(v.w);
  }
  float h[DS];
  const size_t base = ((size_t)(b * NC + c) * DS) * DI + d;
#pragma unroll
  for (int s = 0; s < DS; s++) h[s] = HE[base + (size_t)s * DI];
  const float Dv = Dvec[d];
  __syncthreads();

  for (int tt = 0; tt < CL; tt++) {
    const size_t ml = mlbase + tt;
    const float dtv = dtm[ml * DI + d];
    const float u   = (float)xc[ml * DI + d];
    const float du  = dtv * u;
    float p = 0.f;
#pragma unroll
    for (int s = 0; s < DS; s++) {
      h[s] = __expf(dtv * a[s]) * h[s] + du * Bs[tt][s];
      p += h[s] * Cs[tt][s];
    }
    const float zv = zbuf[ml * DI + d];
    const float sil = zv / (1.f + __expf(-zv));
    y[ml * DI + d] = (_Float16)((p + u * Dv) * sil);
  }
}

// ---------------------------------------------------------------------------
// Launch
// ---------------------------------------------------------------------------
extern "C" void kernel_launch(void* const* d_in, const int* in_sizes, int n_in,
                              void* d_out, int out_size, void* d_ws, size_t ws_size,
                              hipStream_t stream) {
  const float* x         = (const float*)d_in[0];
  const float* ln_w      = (const float*)d_in[1];
  const float* ln_b      = (const float*)d_in[2];
  const float* in_proj_w = (const float*)d_in[3];   // (4096, 1024)
  const float* conv_w    = (const float*)d_in[4];   // (2048, 1, 4)
  const float* conv_b    = (const float*)d_in[5];
  const float* x_proj_w  = (const float*)d_in[6];   // (96, 2048)
  const float* dt_proj_w = (const float*)d_in[7];   // (2048, 64)
  const float* dt_proj_b = (const float*)d_in[8];
  const float* A_log     = (const float*)d_in[9];   // (2048, 16)
  const float* Dvec      = (const float*)d_in[10];
  const float* out_proj_w= (const float*)d_in[11];  // (1024, 2048)
  float* out = (float*)d_out;

  // workspace layout (f32 slots; total ~18.4M floats = 73.5 MB)
  float* ws = (float*)d_ws;
  float*     zbuf    = ws;                                  // 4,194,304
  float*     xinbuf  = zbuf + 4194304;                      // 4,194,304
  //   xinbuf dead after conv -> reused:
  float*     HE      = xinbuf;                              // 2,097,152 f32
  _Float16*  y_h     = (_Float16*)(xinbuf + 2097152);       // 4,194,304 halfs
  _Float16*  xc_h    = (_Float16*)(xinbuf + 4194304);       // 4,194,304 halfs (2,097,152 slots)
  float*     dtb     = xinbuf + 4194304 + 2097152;          // 4,194,304
  _Float16*  h_h     = (_Float16*)dtb;                      // 2,097,152 halfs (aliases dtb; dead before dt gemm)
  float*     x_dbl   = dtb + 4194304;                       // 196,608
  float*     SA      = x_dbl + 196608;                      // 131,072
  _Float16*  dtr_h   = (_Float16*)(SA + 131072);            // 131,072 halfs (65,536 slots)
  _Float16*  w_in_h  = (_Float16*)(SA + 131072 + 65536);    // 4,194,304 halfs
  _Float16*  w_out_h = w_in_h + 4194304;                    // 2,097,152 halfs
  _Float16*  w_xp_h  = w_out_h + 2097152;                   // 196,608 halfs
  _Float16*  w_dt_h  = w_xp_h + 196608;                     // 131,072 halfs

  // 0. weight conversions f32 -> f16
  f2h_kernel<<<4194304 / 1024, 256, 0, stream>>>(in_proj_w,  w_in_h,  4194304 / 4);
  f2h_kernel<<<2097152 / 1024, 256, 0, stream>>>(out_proj_w, w_out_h, 2097152 / 4);
  f2h_kernel<<< 196608 / 1024, 256, 0, stream>>>(x_proj_w,   w_xp_h,   196608 / 4);
  f2h_kernel<<< 131072 / 1024, 256, 0, stream>>>(dt_proj_w,  w_dt_h,   131072 / 4);

  // 1. layernorm -> f16
  ln_kernel<<<MR, 256, 0, stream>>>(x, ln_w, ln_b, h_h);

  // 2. in_proj (two halves: x_in rows 0..2047, z rows 2048..4095)
  gemm_mfma<0><<<dim3(DI / 128, MR / 128, 1), 256, 0, stream>>>(
      h_h, w_in_h, xinbuf, DI, nullptr, MR, DI, DM, DM);
  gemm_mfma<0><<<dim3(DI / 128, MR / 128, 1), 256, 0, stream>>>(
      h_h, w_in_h + (size_t)DI * DM, zbuf, DI, nullptr, MR, DI, DM, DM);

  // 3. conv + silu -> xc_h (f16)
  conv_silu_kernel<<<(MR * DI) / 256, 256, 0, stream>>>(xinbuf, conv_w, conv_b, xc_h);

  // 4. x_proj, split-K (8 slices of 256) with atomic f32 accumulation
  zero_kernel<<<(MR * XDBL / 4 + 255) / 256, 256, 0, stream>>>(x_dbl, MR * XDBL / 4);
  gemm_mfma<3><<<dim3(1, MR / 128, 8), 256, 0, stream>>>(
      xc_h, w_xp_h, x_dbl, XDBL, nullptr, MR, XDBL, DI, DI / 8);

  // 5. dt: extract dt-rank cols to f16, then MFMA + softplus epilogue
  dtext_kernel<<<(MR * DTR) / 256, 256, 0, stream>>>(x_dbl, dtr_h);
  gemm_mfma<1><<<dim3(DI / 128, MR / 128, 1), 256, 0, stream>>>(
      dtr_h, w_dt_h, dtb, DI, dt_proj_b, MR, DI, DTR, DTR);

  // 6. chunked selective scan
  scan_phase1<<<NB * NC * (DI / 256), 256, 0, stream>>>(
      xc_h, x_dbl, dtb, A_log, HE, SA);
  scan_phase2<<<(NB * DS * DI) / 256, 256, 0, stream>>>(A_log, SA, HE);
  scan_phase3<<<NB * NC * (DI / 256), 256, 0, stream>>>(
      xc_h, x_dbl, dtb, zbuf, A_log, Dvec, HE, y_h);

  // 7. out_proj + residual
  gemm_mfma<2><<<dim3(DM / 128, MR / 128, 1), 256, 0, stream>>>(
      y_h, w_out_h, out, DM, x, MR, DM, DI, DI);
}

// Round 4
// 305.824 us; speedup vs baseline: 5.1806x; 1.0794x over previous
//
#include <hip/hip_runtime.h>
#include <hip/hip_bf16.h>
#include <math.h>

// Problem constants (from reference)
#define DM   1024        // d_model
#define DI   2048        // d_inner
#define DS   16          // d_state
#define DTR  64          // dt_rank
#define NB   2           // batch
#define LL   1024        // seq len
#define MR   (NB*LL)     // 2048 rows (b*l flattened)
#define XDBL 96          // dt_rank + 2*d_state
#define NC   32          // scan chunks
#define CL   32          // chunk length (NC*CL == LL)

typedef _Float16 half8  __attribute__((ext_vector_type(8)));
typedef _Float16 half4v __attribute__((ext_vector_type(4)));
typedef float    floatx4 __attribute__((ext_vector_type(4)));

__device__ __forceinline__ void gload_lds16(const void* g, void* l) {
  __builtin_amdgcn_global_load_lds(
      (const __attribute__((address_space(1))) void*)g,
      (__attribute__((address_space(3))) void*)l, 16, 0, 0);
}

// ---------------------------------------------------------------------------
// Fused f32->f16 conversion of all 4 weight matrices (one dispatch).
// Sizes in float4 units: in_proj 1048576, out_proj 524288, x_proj 49152,
// dt_proj 32768 -> total 1654784.
// ---------------------------------------------------------------------------
__global__ __launch_bounds__(256) void f2h_all(
    const float* __restrict__ s0, const float* __restrict__ s1,
    const float* __restrict__ s2, const float* __restrict__ s3,
    _Float16* __restrict__ d0, _Float16* __restrict__ d1,
    _Float16* __restrict__ d2, _Float16* __restrict__ d3) {
  int i = blockIdx.x * 256 + threadIdx.x;
  const int N0 = 1048576, N1 = 524288, N2 = 49152, N3 = 32768;
  const float* s; _Float16* d; int off;
  if (i < N0)                { s = s0; d = d0; off = i; }
  else if (i < N0+N1)        { s = s1; d = d1; off = i - N0; }
  else if (i < N0+N1+N2)     { s = s2; d = d2; off = i - N0 - N1; }
  else if (i < N0+N1+N2+N3)  { s = s3; d = d3; off = i - N0 - N1 - N2; }
  else return;
  float4 v = ((const float4*)s)[off];
  half4v h = {(_Float16)v.x, (_Float16)v.y, (_Float16)v.z, (_Float16)v.w};
  ((half4v*)d)[off] = h;
}

// ---------------------------------------------------------------------------
// Prep: out = x (residual init for atomic out_proj) and x_dbl = 0 (split-K).
// float4 units: copy 524288, zero 49152.
// ---------------------------------------------------------------------------
__global__ __launch_bounds__(256) void prep_kernel(
    const float* __restrict__ x, float* __restrict__ out,
    float* __restrict__ xdbl) {
  int i = blockIdx.x * 256 + threadIdx.x;
  if (i < 524288) ((float4*)out)[i] = ((const float4*)x)[i];
  else if (i < 524288 + 49152)
    ((float4*)xdbl)[i - 524288] = make_float4(0.f, 0.f, 0.f, 0.f);
}

// x_dbl[:, 0:64] f32 -> compact f16 [MR][64]
__global__ __launch_bounds__(256) void dtext_kernel(
    const float* __restrict__ xdbl, _Float16* __restrict__ dtr) {
  int idx = blockIdx.x * 256 + threadIdx.x;   // MR*DTR
  int m = idx >> 6, c = idx & 63;
  dtr[idx] = (_Float16)xdbl[(size_t)m * XDBL + c];
}

// ---------------------------------------------------------------------------
// LayerNorm -> f16 output
// ---------------------------------------------------------------------------
__global__ __launch_bounds__(256) void ln_kernel(
    const float* __restrict__ x, const float* __restrict__ w,
    const float* __restrict__ b, _Float16* __restrict__ h) {
  __shared__ float sA[4], sB[4];
  const int m = blockIdx.x;
  const float* xr = x + (size_t)m * DM;
  float s = 0.f, ss = 0.f;
  for (int i = threadIdx.x; i < DM; i += 256) {
    float v = xr[i];
    s += v; ss += v * v;
  }
  for (int o = 32; o > 0; o >>= 1) {
    s  += __shfl_down(s, o, 64);
    ss += __shfl_down(ss, o, 64);
  }
  const int wid = threadIdx.x >> 6, lid = threadIdx.x & 63;
  if (lid == 0) { sA[wid] = s; sB[wid] = ss; }
  __syncthreads();
  if (threadIdx.x == 0) {
    float S = sA[0] + sA[1] + sA[2] + sA[3];
    float SS = sB[0] + sB[1] + sB[2] + sB[3];
    float mu = S / DM;
    sA[0] = mu;
    sB[0] = rsqrtf(SS / DM - mu * mu + 1e-5f);
  }
  __syncthreads();
  const float mu = sA[0], rs = sB[0];
  for (int i = threadIdx.x; i < DM; i += 256)
    h[(size_t)m * DM + i] = (_Float16)((xr[i] - mu) * rs * w[i] + b[i]);
}

// ---------------------------------------------------------------------------
// MFMA f16 GEMM: C[m,n] = sum_k A[m,k]*W[n,k], fp32 accumulate.
// 128x128 tile, BK=32, 4 waves each 64x64 (4x4 tiles of 16x16x32).
// EPI 0: dual f16 store (n<DI -> C, else C2; compact DI-wide rows)
// EPI 1: f32 store softplus(acc + extra[n])
// EPI 3: f32 atomicAdd (split-K over blockIdx.z; C pre-initialized)
// M multiple of 128; N guarded (W row reads clamped).
// ---------------------------------------------------------------------------
template <int EPI>
__global__ __launch_bounds__(256) void gemm_mfma(
    const _Float16* __restrict__ A,   // [M][K]
    const _Float16* __restrict__ W,   // [N][K]
    void* __restrict__ Cv, void* __restrict__ C2v,
    const float* __restrict__ extra, int ldc,
    int M, int N, int K, int kchunk) {
  __shared__ alignas(16) _Float16 As[128 * 32];
  __shared__ alignas(16) _Float16 Ws[128 * 32];
  const int t = threadIdx.x;
  const int wave = t >> 6, lane = t & 63;
  const int m0 = blockIdx.y * 128, n0 = blockIdx.x * 128;
  const int k_beg = blockIdx.z * kchunk;
  const int k_end = min(K, k_beg + kchunk);
  const int wm = (wave >> 1) * 64, wn = (wave & 1) * 64;
  floatx4 acc[4][4];
#pragma unroll
  for (int i = 0; i < 4; i++)
#pragma unroll
    for (int j = 0; j < 4; j++) acc[i][j] = {0.f, 0.f, 0.f, 0.f};

  const int fr = lane & 15;     // row within 16-tile
  const int kc8 = lane >> 4;    // which 8-half k-chunk

  for (int k0 = k_beg; k0 < k_end; k0 += 32) {
#pragma unroll
    for (int j = 0; j < 2; j++) {
      const int slot = (j * 4 + wave) * 64 + lane;
      const int row = slot >> 2, kc = slot & 3;
      const int wrow = (row < N) ? row : 0;   // clamp W reads when N<128
      gload_lds16(A + (size_t)(m0 + row) * K + k0 + kc * 8,
                  &As[(j * 4 + wave) * 512]);
      gload_lds16(W + (size_t)(n0 + wrow) * K + k0 + kc * 8,
                  &Ws[(j * 4 + wave) * 512]);
    }
    __syncthreads();
    half8 af[4], wf[4];
#pragma unroll
    for (int i = 0; i < 4; i++) {
      af[i] = *(const half8*)&As[(wm + i * 16 + fr) * 32 + kc8 * 8];
      wf[i] = *(const half8*)&Ws[(wn + i * 16 + fr) * 32 + kc8 * 8];
    }
#pragma unroll
    for (int i = 0; i < 4; i++)
#pragma unroll
      for (int j = 0; j < 4; j++)
        acc[i][j] = __builtin_amdgcn_mfma_f32_16x16x32_f16(af[i], wf[j], acc[i][j], 0, 0, 0);
    __syncthreads();
  }

  // epilogue: C/D layout col = lane&15, row = (lane>>4)*4 + reg
  const int col = lane & 15, rowq = lane >> 4;
#pragma unroll
  for (int i = 0; i < 4; i++) {
#pragma unroll
    for (int j = 0; j < 4; j++) {
      const int n = n0 + wn + j * 16 + col;
      if (n < N) {
#pragma unroll
        for (int r = 0; r < 4; r++) {
          const int m = m0 + wm + i * 16 + rowq * 4 + r;
          float v = acc[i][j][r];
          if (EPI == 0) {
            if (n < DI) ((_Float16*)Cv )[(size_t)m * DI + n]      = (_Float16)v;
            else        ((_Float16*)C2v)[(size_t)m * DI + n - DI] = (_Float16)v;
          } else if (EPI == 1) {
            v += extra[n];
            v = (v > 20.f) ? v : log1pf(expf(v));   // softplus
            ((float*)Cv)[(size_t)m * ldc + n] = v;
          } else if (EPI == 3) {
            atomicAdd(&((float*)Cv)[(size_t)m * ldc + n], v);
          }
        }
      }
    }
  }
}

// ---------------------------------------------------------------------------
// Depthwise causal conv1d (width 4) + bias + SiLU. f16 in, f16 out.
// ---------------------------------------------------------------------------
__global__ __launch_bounds__(256) void conv_silu_kernel(
    const _Float16* __restrict__ xin, const float* __restrict__ cw,
    const float* __restrict__ cb, _Float16* __restrict__ xc) {
  const int idx = blockIdx.x * 256 + threadIdx.x;   // 0 .. MR*DI-1
  const int d  = idx & (DI - 1);
  const int ml = idx >> 11;
  const int l  = ml & (LL - 1);
  float acc = cb[d];
#pragma unroll
  for (int k = 0; k < 4; k++) {
    int lp = l - 3 + k;
    if (lp >= 0)
      acc += (float)xin[(size_t)(ml - (3 - k)) * DI + d] * cw[d * 4 + k];
  }
  xc[idx] = (_Float16)(acc / (1.f + __expf(-acc)));
}

// ---------------------------------------------------------------------------
// Chunked selective scan, phase 1: per-(b,chunk) local scan with h=0 init.
// ---------------------------------------------------------------------------
__global__ __launch_bounds__(256) void scan_phase1(
    const _Float16* __restrict__ xc,  // x_conv (MR x DI) f16
    const float* __restrict__ xdbl,   // (MR x 96)
    const float* __restrict__ dtm,    // dt after softplus (MR x DI) f32
    const float* __restrict__ A_log,
    float* __restrict__ HE,           // (NB*NC*DS) x DI
    float* __restrict__ SA) {         // (NB*NC) x DI
  __shared__ float Bs[CL][DS];
  const int bi = blockIdx.x;
  const int dblk = bi & 7;
  const int c = (bi >> 3) & (NC - 1);
  const int b = bi >> 8;
  const int t = threadIdx.x;
  const int d = dblk * 256 + t;
  const int mlbase = b * LL + c * CL;

  for (int i = t; i < CL * DS; i += 256) {
    int tt = i >> 4, s = i & 15;
    Bs[tt][s] = xdbl[(size_t)(mlbase + tt) * XDBL + DTR + s];
  }

  float a[DS];
  const float4* Ap = (const float4*)(A_log + (size_t)d * DS);
#pragma unroll
  for (int i = 0; i < 4; i++) {
    float4 v = Ap[i];
    a[4 * i + 0] = -__expf(v.x); a[4 * i + 1] = -__expf(v.y);
    a[4 * i + 2] = -__expf(v.z); a[4 * i + 3] = -__expf(v.w);
  }
  float h[DS];
#pragma unroll
  for (int s = 0; s < DS; s++) h[s] = 0.f;
  float S = 0.f;
  __syncthreads();

  for (int tt = 0; tt < CL; tt++) {
    const size_t ml = mlbase + tt;
    const float dtv = dtm[ml * DI + d];
    const float u   = (float)xc[ml * DI + d];
    const float du  = dtv * u;
    S += dtv;
#pragma unroll
    for (int s = 0; s < DS; s++)
      h[s] = __expf(dtv * a[s]) * h[s] + du * Bs[tt][s];
  }
  const size_t base = ((size_t)(b * NC + c) * DS) * DI + d;
#pragma unroll
  for (int s = 0; s < DS; s++) HE[base + (size_t)s * DI] = h[s];
  SA[(size_t)(b * NC + c) * DI + d] = S;
}

// ---------------------------------------------------------------------------
// Phase 2: sequential combine over chunk aggregates; HE becomes carry-in.
// ---------------------------------------------------------------------------
__global__ __launch_bounds__(256) void scan_phase2(
    const float* __restrict__ A_log,
    const float* __restrict__ SA,
    float* __restrict__ HE) {
  const int idx = blockIdx.x * 256 + threadIdx.x;  // NB*DS*DI
  const int d = idx & (DI - 1);
  const int s = (idx >> 11) & (DS - 1);
  const int b = idx >> 15;
  const float a = -__expf(A_log[(size_t)d * DS + s]);
  float Hc = 0.f;
  for (int c = 0; c < NC; c++) {
    const size_t o = ((size_t)(b * NC + c) * DS + s) * DI + d;
    const float he = HE[o];
    const float P = __expf(a * SA[(size_t)(b * NC + c) * DI + d]);
    HE[o] = Hc;
    Hc = P * Hc + he;
  }
}

// ---------------------------------------------------------------------------
// Phase 3: re-run chunks with carry-in; fuse y = (sum_s h*C + u*D)*silu(z).
// ---------------------------------------------------------------------------
__global__ __launch_bounds__(256) void scan_phase3(
    const _Float16* __restrict__ xc,
    const float* __restrict__ xdbl,
    const float* __restrict__ dtm,
    const _Float16* __restrict__ zbuf,  // z (MR x DI) f16
    const float* __restrict__ A_log,
    const float* __restrict__ Dvec,
    const float* __restrict__ HE,
    _Float16* __restrict__ y) {         // (MR x DI) f16
  __shared__ float Bs[CL][DS];
  __shared__ float Cs[CL][DS];
  const int bi = blockIdx.x;
  const int dblk = bi & 7;
  const int c = (bi >> 3) & (NC - 1);
  const int b = bi >> 8;
  const int t = threadIdx.x;
  const int d = dblk * 256 + t;
  const int mlbase = b * LL + c * CL;

  for (int i = t; i < CL * DS; i += 256) {
    int tt = i >> 4, s = i & 15;
    const size_t ro = (size_t)(mlbase + tt) * XDBL + DTR + s;
    Bs[tt][s] = xdbl[ro];
    Cs[tt][s] = xdbl[ro + DS];
  }

  float a[DS];
  const float4* Ap = (const float4*)(A_log + (size_t)d * DS);
#pragma unroll
  for (int i = 0; i < 4; i++) {
    float4 v = Ap[i];
    a[4 * i + 0] = -__expf(v.x); a[4 * i + 1] = -__expf(v.y);
    a[4 * i + 2] = -__expf(v.z); a[4 * i + 3] = -__expf(v.w);
  }
  float h[DS];
  const size_t base = ((size_t)(b * NC + c) * DS) * DI + d;
#pragma unroll
  for (int s = 0; s < DS; s++) h[s] = HE[base + (size_t)s * DI];
  const float Dv = Dvec[d];
  __syncthreads();

  for (int tt = 0; tt < CL; tt++) {
    const size_t ml = mlbase + tt;
    const float dtv = dtm[ml * DI + d];
    const float u   = (float)xc[ml * DI + d];
    const float du  = dtv * u;
    float p = 0.f;
#pragma unroll
    for (int s = 0; s < DS; s++) {
      h[s] = __expf(dtv * a[s]) * h[s] + du * Bs[tt][s];
      p += h[s] * Cs[tt][s];
    }
    const float zv = (float)zbuf[ml * DI + d];
    const float sil = zv / (1.f + __expf(-zv));
    y[ml * DI + d] = (_Float16)((p + u * Dv) * sil);
  }
}

// ---------------------------------------------------------------------------
// Launch
// ---------------------------------------------------------------------------
extern "C" void kernel_launch(void* const* d_in, const int* in_sizes, int n_in,
                              void* d_out, int out_size, void* d_ws, size_t ws_size,
                              hipStream_t stream) {
  const float* x         = (const float*)d_in[0];
  const float* ln_w      = (const float*)d_in[1];
  const float* ln_b      = (const float*)d_in[2];
  const float* in_proj_w = (const float*)d_in[3];   // (4096, 1024)
  const float* conv_w    = (const float*)d_in[4];   // (2048, 1, 4)
  const float* conv_b    = (const float*)d_in[5];
  const float* x_proj_w  = (const float*)d_in[6];   // (96, 2048)
  const float* dt_proj_w = (const float*)d_in[7];   // (2048, 64)
  const float* dt_proj_b = (const float*)d_in[8];
  const float* A_log     = (const float*)d_in[9];   // (2048, 16)
  const float* Dvec      = (const float*)d_in[10];
  const float* out_proj_w= (const float*)d_in[11];  // (1024, 2048)
  float* out = (float*)d_out;

  // workspace layout (bytes; total ~66.1 MB)
  char* ws = (char*)d_ws;
  _Float16* h_h     = (_Float16*)ws;                 //  4 MB (MR*DM)
  _Float16* xin_h   = (_Float16*)(ws + 4194304);     //  8 MB (MR*DI)
  _Float16* y_h     = xin_h;                         //  aliases xin (dead after conv)
  _Float16* z_h     = (_Float16*)(ws + 12582912);    //  8 MB
  _Float16* xc_h    = (_Float16*)(ws + 20971520);    //  8 MB
  float*    dtb     = (float*)   (ws + 29360128);    // 16 MB (MR*DI f32)
  float*    x_dbl   = (float*)   (ws + 46137344);    //  0.75 MB
  float*    SA      = (float*)   (ws + 46923776);    //  0.5 MB
  _Float16* dtr_h   = (_Float16*)(ws + 47448064);    //  0.25 MB
  float*    HE      = (float*)   (ws + 47710208);    //  8 MB
  _Float16* w_in_h  = (_Float16*)(ws + 56098816);    //  8 MB
  _Float16* w_out_h = (_Float16*)(ws + 64487424);    //  4 MB
  _Float16* w_xp_h  = (_Float16*)(ws + 68681728);    //  0.375 MB
  _Float16* w_dt_h  = (_Float16*)(ws + 69074944);    //  0.25 MB  (end ~69.3 MB)

  // 0. fused weight conversion + prep (residual init, x_dbl zero)
  f2h_all<<<6464, 256, 0, stream>>>(in_proj_w, out_proj_w, x_proj_w, dt_proj_w,
                                    w_in_h, w_out_h, w_xp_h, w_dt_h);
  prep_kernel<<<2240, 256, 0, stream>>>(x, out, x_dbl);

  // 1. layernorm -> f16
  ln_kernel<<<MR, 256, 0, stream>>>(x, ln_w, ln_b, h_h);

  // 2. in_proj: one dispatch, N=4096, dual-store x_in/z f16 (512 blocks)
  gemm_mfma<0><<<dim3(2 * DI / 128, MR / 128, 1), 256, 0, stream>>>(
      h_h, w_in_h, xin_h, z_h, nullptr, 0, MR, 2 * DI, DM, DM);

  // 3. conv + silu -> xc_h (f16)
  conv_silu_kernel<<<(MR * DI) / 256, 256, 0, stream>>>(xin_h, conv_w, conv_b, xc_h);

  // 4. x_proj, split-K 16 with atomic f32 accumulation (256 blocks)
  gemm_mfma<3><<<dim3(1, MR / 128, 16), 256, 0, stream>>>(
      xc_h, w_xp_h, x_dbl, nullptr, nullptr, XDBL, MR, XDBL, DI, DI / 16);

  // 5. dt: extract dt-rank cols to f16, then MFMA + softplus epilogue
  dtext_kernel<<<(MR * DTR) / 256, 256, 0, stream>>>(x_dbl, dtr_h);
  gemm_mfma<1><<<dim3(DI / 128, MR / 128, 1), 256, 0, stream>>>(
      dtr_h, w_dt_h, dtb, nullptr, dt_proj_b, DI, MR, DI, DTR, DTR);

  // 6. chunked selective scan
  scan_phase1<<<NB * NC * (DI / 256), 256, 0, stream>>>(
      xc_h, x_dbl, dtb, A_log, HE, SA);
  scan_phase2<<<(NB * DS * DI) / 256, 256, 0, stream>>>(A_log, SA, HE);
  scan_phase3<<<NB * NC * (DI / 256), 256, 0, stream>>>(
      xc_h, x_dbl, dtb, z_h, A_log, Dvec, HE, y_h);

  // 7. out_proj + residual: split-K 4, atomicAdd into out (= x from prep)
  gemm_mfma<3><<<dim3(DM / 128, MR / 128, 4), 256, 0, stream>>>(
      y_h, w_out_h, out, nullptr, nullptr, DM, MR, DM, DI, DI / 4);
}

// Round 5
// 269.492 us; speedup vs baseline: 5.8791x; 1.1348x over previous
//
#include <hip/hip_runtime.h>
#include <hip/hip_bf16.h>
#include <math.h>

// Problem constants (from reference)
#define DM   1024        // d_model
#define DI   2048        // d_inner
#define DS   16          // d_state
#define DTR  64          // dt_rank
#define NB   2           // batch
#define LL   1024        // seq len
#define MR   (NB*LL)     // 2048 rows (b*l flattened)
#define XDBL 96          // dt_rank + 2*d_state
#define NC   32          // scan chunks
#define CL   32          // chunk length (NC*CL == LL)

typedef _Float16 half8  __attribute__((ext_vector_type(8)));
typedef _Float16 half4v __attribute__((ext_vector_type(4)));
typedef float    floatx4 __attribute__((ext_vector_type(4)));

__device__ __forceinline__ void gload_lds16(const void* g, void* l) {
  __builtin_amdgcn_global_load_lds(
      (const __attribute__((address_space(1))) void*)g,
      (__attribute__((address_space(3))) void*)l, 16, 0, 0);
}

// ---------------------------------------------------------------------------
// Front kernel: LN (blocks 0..2047) + weight f2h + residual init + x_dbl zero.
// float4-unit jobs: in_proj 1048576 | out_proj 524288 | x_proj 49152 |
// dt_proj 32768 | copy-res 524288 | zero 49152  => 2228224 units = 8704 blocks.
// ---------------------------------------------------------------------------
__global__ __launch_bounds__(256) void front_kernel(
    const float* __restrict__ x, const float* __restrict__ ln_w,
    const float* __restrict__ ln_b,
    const float* __restrict__ w_in, const float* __restrict__ w_out,
    const float* __restrict__ w_xp, const float* __restrict__ w_dt,
    _Float16* __restrict__ h_h,
    _Float16* __restrict__ w_in_h, _Float16* __restrict__ w_out_h,
    _Float16* __restrict__ w_xp_h, _Float16* __restrict__ w_dt_h,
    float* __restrict__ out, float* __restrict__ x_dbl) {
  const int blk = blockIdx.x;
  if (blk < MR) {
    // ---- LayerNorm row ----
    __shared__ float sA[4], sB[4];
    const float* xr = x + (size_t)blk * DM;
    float s = 0.f, ss = 0.f;
    for (int i = threadIdx.x; i < DM; i += 256) {
      float v = xr[i];
      s += v; ss += v * v;
    }
    for (int o = 32; o > 0; o >>= 1) {
      s  += __shfl_down(s, o, 64);
      ss += __shfl_down(ss, o, 64);
    }
    const int wid = threadIdx.x >> 6, lid = threadIdx.x & 63;
    if (lid == 0) { sA[wid] = s; sB[wid] = ss; }
    __syncthreads();
    if (threadIdx.x == 0) {
      float S = sA[0] + sA[1] + sA[2] + sA[3];
      float SS = sB[0] + sB[1] + sB[2] + sB[3];
      float mu = S / DM;
      sA[0] = mu;
      sB[0] = rsqrtf(SS / DM - mu * mu + 1e-5f);
    }
    __syncthreads();
    const float mu = sA[0], rs = sB[0];
    for (int i = threadIdx.x; i < DM; i += 256)
      h_h[(size_t)blk * DM + i] = (_Float16)((xr[i] - mu) * rs * ln_w[i] + ln_b[i]);
    return;
  }
  int i = (blk - MR) * 256 + threadIdx.x;
  const int N0 = 1048576, N1 = 524288, N2 = 49152, N3 = 32768, N4 = 524288, N5 = 49152;
  if (i < N0 + N1 + N2 + N3) {
    const float* s; _Float16* d; int off;
    if (i < N0)            { s = w_in;  d = w_in_h;  off = i; }
    else if (i < N0+N1)    { s = w_out; d = w_out_h; off = i - N0; }
    else if (i < N0+N1+N2) { s = w_xp;  d = w_xp_h;  off = i - N0 - N1; }
    else                   { s = w_dt;  d = w_dt_h;  off = i - N0 - N1 - N2; }
    float4 v = ((const float4*)s)[off];
    half4v h = {(_Float16)v.x, (_Float16)v.y, (_Float16)v.z, (_Float16)v.w};
    ((half4v*)d)[off] = h;
  } else if (i < N0+N1+N2+N3+N4) {
    int off = i - (N0+N1+N2+N3);
    ((float4*)out)[off] = ((const float4*)x)[off];    // residual init
  } else if (i < N0+N1+N2+N3+N4+N5) {
    int off = i - (N0+N1+N2+N3+N4);
    ((float4*)x_dbl)[off] = make_float4(0.f, 0.f, 0.f, 0.f);
  }
}

// x_dbl[:, 0:64] f32 -> compact f16 [MR][64]
__global__ __launch_bounds__(256) void dtext_kernel(
    const float* __restrict__ xdbl, _Float16* __restrict__ dtr) {
  int idx = blockIdx.x * 256 + threadIdx.x;   // MR*DTR
  int m = idx >> 6, c = idx & 63;
  dtr[idx] = (_Float16)xdbl[(size_t)m * XDBL + c];
}

// ---------------------------------------------------------------------------
// MFMA f16 GEMM: C[m,n] = sum_k A[m,k]*W[n,k], fp32 accumulate.
// Tile 128 x TN (TN in {64,96,128}), BK=32, 4 waves each 64 x TN/2.
// EPI 0: dual f16 store (n<DI -> C, else C2; compact DI-wide rows)
// EPI 1: f32 store softplus(acc + extra[n])
// EPI 3: f32 atomicAdd (split-K over blockIdx.z; C pre-initialized)
// M multiple of 128. Latency note: narrow TN -> more blocks/CU for overlap.
// ---------------------------------------------------------------------------
template <int EPI, int TN>
__global__ __launch_bounds__(256) void gemm_mfma(
    const _Float16* __restrict__ A,   // [M][K]
    const _Float16* __restrict__ W,   // [N][K]
    void* __restrict__ Cv, void* __restrict__ C2v,
    const float* __restrict__ extra, int ldc,
    int M, int N, int K, int kchunk) {
  constexpr int NT = TN / 32;          // 16-col tiles per wave (2,3,4)
  constexpr int WSLOT = TN / 16;       // W staging slots
  __shared__ alignas(16) _Float16 As[128 * 32];
  __shared__ alignas(16) _Float16 Ws[TN * 32];
  const int t = threadIdx.x;
  const int wave = t >> 6, lane = t & 63;
  const int m0 = blockIdx.y * 128, n0 = blockIdx.x * TN;
  const int k_beg = blockIdx.z * kchunk;
  const int k_end = min(K, k_beg + kchunk);
  const int wm = (wave >> 1) * 64, wn = (wave & 1) * (TN / 2);
  floatx4 acc[4][NT];
#pragma unroll
  for (int i = 0; i < 4; i++)
#pragma unroll
    for (int j = 0; j < NT; j++) acc[i][j] = {0.f, 0.f, 0.f, 0.f};

  const int fr = lane & 15;     // row within 16-tile
  const int kc8 = lane >> 4;    // which 8-half k-chunk

  for (int k0 = k_beg; k0 < k_end; k0 += 32) {
    // stage A: 8 slots of 64 lanes x 16B
#pragma unroll
    for (int sl = wave; sl < 8; sl += 4) {
      const int idx = sl * 64 + lane;
      const int row = idx >> 2, kc = idx & 3;
      gload_lds16(A + (size_t)(m0 + row) * K + k0 + kc * 8, &As[sl * 512]);
    }
    // stage W: TN/16 slots
#pragma unroll
    for (int sl = wave; sl < WSLOT; sl += 4) {
      const int idx = sl * 64 + lane;
      const int row = idx >> 2, kc = idx & 3;
      const int wrow = (n0 + row < N) ? row : 0;   // safety clamp
      gload_lds16(W + (size_t)(n0 + wrow) * K + k0 + kc * 8, &Ws[sl * 512]);
    }
    __syncthreads();
    half8 af[4], wf[NT];
#pragma unroll
    for (int i = 0; i < 4; i++)
      af[i] = *(const half8*)&As[(wm + i * 16 + fr) * 32 + kc8 * 8];
#pragma unroll
    for (int j = 0; j < NT; j++)
      wf[j] = *(const half8*)&Ws[(wn + j * 16 + fr) * 32 + kc8 * 8];
#pragma unroll
    for (int i = 0; i < 4; i++)
#pragma unroll
      for (int j = 0; j < NT; j++)
        acc[i][j] = __builtin_amdgcn_mfma_f32_16x16x32_f16(af[i], wf[j], acc[i][j], 0, 0, 0);
    __syncthreads();
  }

  // epilogue: C/D layout col = lane&15, row = (lane>>4)*4 + reg
  const int col = lane & 15, rowq = lane >> 4;
#pragma unroll
  for (int i = 0; i < 4; i++) {
#pragma unroll
    for (int j = 0; j < NT; j++) {
      const int n = n0 + wn + j * 16 + col;
      if (n < N) {
#pragma unroll
        for (int r = 0; r < 4; r++) {
          const int m = m0 + wm + i * 16 + rowq * 4 + r;
          float v = acc[i][j][r];
          if (EPI == 0) {
            if (n < DI) ((_Float16*)Cv )[(size_t)m * DI + n]      = (_Float16)v;
            else        ((_Float16*)C2v)[(size_t)m * DI + n - DI] = (_Float16)v;
          } else if (EPI == 1) {
            v += extra[n];
            v = (v > 20.f) ? v : log1pf(expf(v));   // softplus
            ((float*)Cv)[(size_t)m * ldc + n] = v;
          } else if (EPI == 3) {
            atomicAdd(&((float*)Cv)[(size_t)m * ldc + n], v);
          }
        }
      }
    }
  }
}

// ---------------------------------------------------------------------------
// Depthwise causal conv1d (width 4) + bias + SiLU. f16 in, f16 out.
// ---------------------------------------------------------------------------
__global__ __launch_bounds__(256) void conv_silu_kernel(
    const _Float16* __restrict__ xin, const float* __restrict__ cw,
    const float* __restrict__ cb, _Float16* __restrict__ xc) {
  const int idx = blockIdx.x * 256 + threadIdx.x;   // 0 .. MR*DI-1
  const int d  = idx & (DI - 1);
  const int ml = idx >> 11;
  const int l  = ml & (LL - 1);
  float acc = cb[d];
#pragma unroll
  for (int k = 0; k < 4; k++) {
    int lp = l - 3 + k;
    if (lp >= 0)
      acc += (float)xin[(size_t)(ml - (3 - k)) * DI + d] * cw[d * 4 + k];
  }
  xc[idx] = (_Float16)(acc / (1.f + __expf(-acc)));
}

// ---------------------------------------------------------------------------
// Load per-channel A row; detect S4D-real init a[s] == -(s+1) (uniform).
// ---------------------------------------------------------------------------
__device__ __forceinline__ bool load_a(const float* __restrict__ A_log, int d,
                                       float* a) {
  const float4* Ap = (const float4*)(A_log + (size_t)d * DS);
  bool fast = true;
#pragma unroll
  for (int i = 0; i < 4; i++) {
    float4 v = Ap[i];
    a[4 * i + 0] = -__expf(v.x); a[4 * i + 1] = -__expf(v.y);
    a[4 * i + 2] = -__expf(v.z); a[4 * i + 3] = -__expf(v.w);
  }
#pragma unroll
  for (int s = 0; s < DS; s++)
    fast = fast && (fabsf(a[s] + (float)(s + 1)) < 1e-4f);
  return fast;
}

// ---------------------------------------------------------------------------
// Chunked selective scan, phase 1: per-(b,chunk) local scan with h=0 init.
// Fast path: exp(dt*a[s]) = r^(s+1), r = exp(-dt)  (1 exp + 15 mul vs 16 exp).
// ---------------------------------------------------------------------------
__global__ __launch_bounds__(256) void scan_phase1(
    const _Float16* __restrict__ xc,  // x_conv (MR x DI) f16
    const float* __restrict__ xdbl,   // (MR x 96)
    const float* __restrict__ dtm,    // dt after softplus (MR x DI) f32
    const float* __restrict__ A_log,
    float* __restrict__ HE,           // (NB*NC*DS) x DI
    float* __restrict__ SA) {         // (NB*NC) x DI
  __shared__ float Bs[CL][DS];
  const int bi = blockIdx.x;
  const int dblk = bi & 7;
  const int c = (bi >> 3) & (NC - 1);
  const int b = bi >> 8;
  const int t = threadIdx.x;
  const int d = dblk * 256 + t;
  const int mlbase = b * LL + c * CL;

  for (int i = t; i < CL * DS; i += 256) {
    int tt = i >> 4, s = i & 15;
    Bs[tt][s] = xdbl[(size_t)(mlbase + tt) * XDBL + DTR + s];
  }

  float a[DS];
  const bool fast = load_a(A_log, d, a);
  float h[DS];
#pragma unroll
  for (int s = 0; s < DS; s++) h[s] = 0.f;
  float S = 0.f;
  __syncthreads();

  if (fast) {
    for (int tt = 0; tt < CL; tt++) {
      const size_t ml = mlbase + tt;
      const float dtv = dtm[ml * DI + d];
      const float u   = (float)xc[ml * DI + d];
      const float du  = dtv * u;
      S += dtv;
      const float r = __expf(-dtv);
      float P = 1.f;
#pragma unroll
      for (int s = 0; s < DS; s++) {
        P *= r;
        h[s] = P * h[s] + du * Bs[tt][s];
      }
    }
  } else {
    for (int tt = 0; tt < CL; tt++) {
      const size_t ml = mlbase + tt;
      const float dtv = dtm[ml * DI + d];
      const float u   = (float)xc[ml * DI + d];
      const float du  = dtv * u;
      S += dtv;
#pragma unroll
      for (int s = 0; s < DS; s++)
        h[s] = __expf(dtv * a[s]) * h[s] + du * Bs[tt][s];
    }
  }
  const size_t base = ((size_t)(b * NC + c) * DS) * DI + d;
#pragma unroll
  for (int s = 0; s < DS; s++) HE[base + (size_t)s * DI] = h[s];
  SA[(size_t)(b * NC + c) * DI + d] = S;
}

// ---------------------------------------------------------------------------
// Phase 2: sequential combine over chunk aggregates; HE becomes carry-in.
// ---------------------------------------------------------------------------
__global__ __launch_bounds__(256) void scan_phase2(
    const float* __restrict__ A_log,
    const float* __restrict__ SA,
    float* __restrict__ HE) {
  const int idx = blockIdx.x * 256 + threadIdx.x;  // NB*DS*DI
  const int d = idx & (DI - 1);
  const int s = (idx >> 11) & (DS - 1);
  const int b = idx >> 15;
  const float a = -__expf(A_log[(size_t)d * DS + s]);
  float Hc = 0.f;
  for (int c = 0; c < NC; c++) {
    const size_t o = ((size_t)(b * NC + c) * DS + s) * DI + d;
    const float he = HE[o];
    const float P = __expf(a * SA[(size_t)(b * NC + c) * DI + d]);
    HE[o] = Hc;
    Hc = P * Hc + he;
  }
}

// ---------------------------------------------------------------------------
// Phase 3: re-run chunks with carry-in; fuse y = (sum_s h*C + u*D)*silu(z).
// ---------------------------------------------------------------------------
__global__ __launch_bounds__(256) void scan_phase3(
    const _Float16* __restrict__ xc,
    const float* __restrict__ xdbl,
    const float* __restrict__ dtm,
    const _Float16* __restrict__ zbuf,  // z (MR x DI) f16
    const float* __restrict__ A_log,
    const float* __restrict__ Dvec,
    const float* __restrict__ HE,
    _Float16* __restrict__ y) {         // (MR x DI) f16
  __shared__ float Bs[CL][DS];
  __shared__ float Cs[CL][DS];
  const int bi = blockIdx.x;
  const int dblk = bi & 7;
  const int c = (bi >> 3) & (NC - 1);
  const int b = bi >> 8;
  const int t = threadIdx.x;
  const int d = dblk * 256 + t;
  const int mlbase = b * LL + c * CL;

  for (int i = t; i < CL * DS; i += 256) {
    int tt = i >> 4, s = i & 15;
    const size_t ro = (size_t)(mlbase + tt) * XDBL + DTR + s;
    Bs[tt][s] = xdbl[ro];
    Cs[tt][s] = xdbl[ro + DS];
  }

  float a[DS];
  const bool fast = load_a(A_log, d, a);
  float h[DS];
  const size_t base = ((size_t)(b * NC + c) * DS) * DI + d;
#pragma unroll
  for (int s = 0; s < DS; s++) h[s] = HE[base + (size_t)s * DI];
  const float Dv = Dvec[d];
  __syncthreads();

  if (fast) {
    for (int tt = 0; tt < CL; tt++) {
      const size_t ml = mlbase + tt;
      const float dtv = dtm[ml * DI + d];
      const float u   = (float)xc[ml * DI + d];
      const float du  = dtv * u;
      const float r = __expf(-dtv);
      float P = 1.f, p = 0.f;
#pragma unroll
      for (int s = 0; s < DS; s++) {
        P *= r;
        h[s] = P * h[s] + du * Bs[tt][s];
        p += h[s] * Cs[tt][s];
      }
      const float zv = (float)zbuf[ml * DI + d];
      const float sil = zv / (1.f + __expf(-zv));
      y[ml * DI + d] = (_Float16)((p + u * Dv) * sil);
    }
  } else {
    for (int tt = 0; tt < CL; tt++) {
      const size_t ml = mlbase + tt;
      const float dtv = dtm[ml * DI + d];
      const float u   = (float)xc[ml * DI + d];
      const float du  = dtv * u;
      float p = 0.f;
#pragma unroll
      for (int s = 0; s < DS; s++) {
        h[s] = __expf(dtv * a[s]) * h[s] + du * Bs[tt][s];
        p += h[s] * Cs[tt][s];
      }
      const float zv = (float)zbuf[ml * DI + d];
      const float sil = zv / (1.f + __expf(-zv));
      y[ml * DI + d] = (_Float16)((p + u * Dv) * sil);
    }
  }
}

// ---------------------------------------------------------------------------
// Launch
// ---------------------------------------------------------------------------
extern "C" void kernel_launch(void* const* d_in, const int* in_sizes, int n_in,
                              void* d_out, int out_size, void* d_ws, size_t ws_size,
                              hipStream_t stream) {
  const float* x         = (const float*)d_in[0];
  const float* ln_w      = (const float*)d_in[1];
  const float* ln_b      = (const float*)d_in[2];
  const float* in_proj_w = (const float*)d_in[3];   // (4096, 1024)
  const float* conv_w    = (const float*)d_in[4];   // (2048, 1, 4)
  const float* conv_b    = (const float*)d_in[5];
  const float* x_proj_w  = (const float*)d_in[6];   // (96, 2048)
  const float* dt_proj_w = (const float*)d_in[7];   // (2048, 64)
  const float* dt_proj_b = (const float*)d_in[8];
  const float* A_log     = (const float*)d_in[9];   // (2048, 16)
  const float* Dvec      = (const float*)d_in[10];
  const float* out_proj_w= (const float*)d_in[11];  // (1024, 2048)
  float* out = (float*)d_out;

  // workspace layout (bytes; total ~69.3 MB)
  char* ws = (char*)d_ws;
  _Float16* h_h     = (_Float16*)ws;                 //  4 MB (MR*DM)
  _Float16* xin_h   = (_Float16*)(ws + 4194304);     //  8 MB (MR*DI)
  _Float16* y_h     = xin_h;                         //  aliases xin (dead after conv)
  _Float16* z_h     = (_Float16*)(ws + 12582912);    //  8 MB
  _Float16* xc_h    = (_Float16*)(ws + 20971520);    //  8 MB
  float*    dtb     = (float*)   (ws + 29360128);    // 16 MB (MR*DI f32)
  float*    x_dbl   = (float*)   (ws + 46137344);    //  0.75 MB
  float*    SA      = (float*)   (ws + 46923776);    //  0.5 MB
  _Float16* dtr_h   = (_Float16*)(ws + 47448064);    //  0.25 MB
  float*    HE      = (float*)   (ws + 47710208);    //  8 MB
  _Float16* w_in_h  = (_Float16*)(ws + 56098816);    //  8 MB
  _Float16* w_out_h = (_Float16*)(ws + 64487424);    //  4 MB
  _Float16* w_xp_h  = (_Float16*)(ws + 68681728);    //  0.375 MB
  _Float16* w_dt_h  = (_Float16*)(ws + 69074944);    //  0.25 MB

  // 0+1. fused: layernorm + weight f2h + residual init + x_dbl zero
  front_kernel<<<MR + 8704, 256, 0, stream>>>(
      x, ln_w, ln_b, in_proj_w, out_proj_w, x_proj_w, dt_proj_w,
      h_h, w_in_h, w_out_h, w_xp_h, w_dt_h, out, x_dbl);

  // 2. in_proj: N=4096, tile 128x64 -> 1024 blocks (4/CU), dual f16 store
  gemm_mfma<0, 64><<<dim3(2 * DI / 64, MR / 128, 1), 256, 0, stream>>>(
      h_h, w_in_h, xin_h, z_h, nullptr, 0, MR, 2 * DI, DM, DM);

  // 3. conv + silu -> xc_h (f16)
  conv_silu_kernel<<<(MR * DI) / 256, 256, 0, stream>>>(xin_h, conv_w, conv_b, xc_h);

  // 4. x_proj: tile 128x96 (exact N), split-K 16, atomic f32 (256 blocks)
  gemm_mfma<3, 96><<<dim3(1, MR / 128, 16), 256, 0, stream>>>(
      xc_h, w_xp_h, x_dbl, nullptr, nullptr, XDBL, MR, XDBL, DI, DI / 16);

  // 5. dt: extract dt-rank cols to f16, then MFMA + softplus (tile 128x64)
  dtext_kernel<<<(MR * DTR) / 256, 256, 0, stream>>>(x_dbl, dtr_h);
  gemm_mfma<1, 64><<<dim3(DI / 64, MR / 128, 1), 256, 0, stream>>>(
      dtr_h, w_dt_h, dtb, nullptr, dt_proj_b, DI, MR, DI, DTR, DTR);

  // 6. chunked selective scan
  scan_phase1<<<NB * NC * (DI / 256), 256, 0, stream>>>(
      xc_h, x_dbl, dtb, A_log, HE, SA);
  scan_phase2<<<(NB * DS * DI) / 256, 256, 0, stream>>>(A_log, SA, HE);
  scan_phase3<<<NB * NC * (DI / 256), 256, 0, stream>>>(
      xc_h, x_dbl, dtb, z_h, A_log, Dvec, HE, y_h);

  // 7. out_proj + residual: tile 128x64, split-K 4 -> 1024 blocks, atomicAdd
  gemm_mfma<3, 64><<<dim3(DM / 64, MR / 128, 4), 256, 0, stream>>>(
      y_h, w_out_h, out, nullptr, nullptr, DM, MR, DM, DI, DI / 4);
}

// Round 6
// 246.132 us; speedup vs baseline: 6.4371x; 1.0949x over previous
//
#include <hip/hip_runtime.h>
#include <hip/hip_bf16.h>
#include <math.h>

// Problem constants (from reference)
#define DM   1024        // d_model
#define DI   2048        // d_inner
#define DS   16          // d_state
#define DTR  64          // dt_rank
#define NB   2           // batch
#define LL   1024        // seq len
#define MR   (NB*LL)     // 2048 rows (b*l flattened)
#define XDBL 96          // dt_rank + 2*d_state
#define NC   32          // scan chunks
#define CL   32          // chunk length (NC*CL == LL)

typedef _Float16 half8  __attribute__((ext_vector_type(8)));
typedef _Float16 half4v __attribute__((ext_vector_type(4)));
typedef float    floatx4 __attribute__((ext_vector_type(4)));

__device__ __forceinline__ void gload_lds16(const void* g, void* l) {
  __builtin_amdgcn_global_load_lds(
      (const __attribute__((address_space(1))) void*)g,
      (__attribute__((address_space(3))) void*)l, 16, 0, 0);
}

// ---------------------------------------------------------------------------
// Front kernel: LN (blocks 0..2047) + weight f2h.
// float4-unit jobs: in 1048576 | out 524288 | xp 49152 | dt 32768 = 1654784
// => 6464 blocks after the LN range.
// ---------------------------------------------------------------------------
__global__ __launch_bounds__(256) void front_kernel(
    const float* __restrict__ x, const float* __restrict__ ln_w,
    const float* __restrict__ ln_b,
    const float* __restrict__ w_in, const float* __restrict__ w_out,
    const float* __restrict__ w_xp, const float* __restrict__ w_dt,
    _Float16* __restrict__ h_h,
    _Float16* __restrict__ w_in_h, _Float16* __restrict__ w_out_h,
    _Float16* __restrict__ w_xp_h, _Float16* __restrict__ w_dt_h) {
  const int blk = blockIdx.x;
  if (blk < MR) {
    __shared__ float sA[4], sB[4];
    const float* xr = x + (size_t)blk * DM;
    float s = 0.f, ss = 0.f;
    for (int i = threadIdx.x; i < DM; i += 256) {
      float v = xr[i];
      s += v; ss += v * v;
    }
    for (int o = 32; o > 0; o >>= 1) {
      s  += __shfl_down(s, o, 64);
      ss += __shfl_down(ss, o, 64);
    }
    const int wid = threadIdx.x >> 6, lid = threadIdx.x & 63;
    if (lid == 0) { sA[wid] = s; sB[wid] = ss; }
    __syncthreads();
    if (threadIdx.x == 0) {
      float S = sA[0] + sA[1] + sA[2] + sA[3];
      float SS = sB[0] + sB[1] + sB[2] + sB[3];
      float mu = S / DM;
      sA[0] = mu;
      sB[0] = rsqrtf(SS / DM - mu * mu + 1e-5f);
    }
    __syncthreads();
    const float mu = sA[0], rs = sB[0];
    for (int i = threadIdx.x; i < DM; i += 256)
      h_h[(size_t)blk * DM + i] = (_Float16)((xr[i] - mu) * rs * ln_w[i] + ln_b[i]);
    return;
  }
  int i = (blk - MR) * 256 + threadIdx.x;
  const int N0 = 1048576, N1 = 524288, N2 = 49152, N3 = 32768;
  const float* s; _Float16* d; int off;
  if (i < N0)            { s = w_in;  d = w_in_h;  off = i; }
  else if (i < N0+N1)    { s = w_out; d = w_out_h; off = i - N0; }
  else if (i < N0+N1+N2) { s = w_xp;  d = w_xp_h;  off = i - N0 - N1; }
  else if (i < N0+N1+N2+N3) { s = w_dt; d = w_dt_h; off = i - N0 - N1 - N2; }
  else return;
  float4 v = ((const float4*)s)[off];
  half4v h = {(_Float16)v.x, (_Float16)v.y, (_Float16)v.z, (_Float16)v.w};
  ((half4v*)d)[off] = h;
}

// ---------------------------------------------------------------------------
// MFMA f16 GEMM, double-buffered LDS pipeline.
// C[m,n] = sum_k A[m,k]*W[n,k], fp32 accumulate. Tile 128 x TN, BK=32,
// 4 waves each 64 x TN/2. Prefetch k+1 overlaps compute of k (the vmcnt(0)
// drain before each barrier then waits on a load issued one full compute
// phase earlier).
// EPI 0: dual f16 store (n<DI -> Cv, else C2v; compact DI-wide rows)
// EPI 1: f32 store softplus(acc + extra[n])
// EPI 4: f32 partial store at Cv + blockIdx.z*M*ldc (split-K, no atomics)
// ---------------------------------------------------------------------------
template <int EPI, int TN>
__global__ __launch_bounds__(256) void gemm_mfma(
    const _Float16* __restrict__ A,   // [M][K]
    const _Float16* __restrict__ W,   // [N][K]
    void* __restrict__ Cv, void* __restrict__ C2v,
    const float* __restrict__ extra, int ldc,
    int M, int N, int K, int kchunk) {
  constexpr int NT = TN / 32;          // 16-col tiles per wave
  constexpr int WSLOT = TN / 16;       // W staging slots (512 halves each)
  __shared__ alignas(16) _Float16 As[2][128 * 32];
  __shared__ alignas(16) _Float16 Ws[2][TN * 32];
  const int t = threadIdx.x;
  const int wave = t >> 6, lane = t & 63;
  const int m0 = blockIdx.y * 128, n0 = blockIdx.x * TN;
  const int k_beg = blockIdx.z * kchunk;
  const int nk = kchunk >> 5;
  const int wm = (wave >> 1) * 64, wn = (wave & 1) * (TN / 2);
  floatx4 acc[4][NT];
#pragma unroll
  for (int i = 0; i < 4; i++)
#pragma unroll
    for (int j = 0; j < NT; j++) acc[i][j] = {0.f, 0.f, 0.f, 0.f};

  const int fr = lane & 15;     // row within 16-tile
  const int kc8 = lane >> 4;    // which 8-half k-chunk

  auto stage = [&](int buf, int k0) {
    for (int sl = wave; sl < 8; sl += 4) {
      const int idx = sl * 64 + lane;
      const int row = idx >> 2, kc = idx & 3;
      gload_lds16(A + (size_t)(m0 + row) * K + k0 + kc * 8, &As[buf][sl * 512]);
    }
    for (int sl = wave; sl < WSLOT; sl += 4) {
      const int idx = sl * 64 + lane;
      const int row = idx >> 2, kc = idx & 3;
      const int wrow = (n0 + row < N) ? row : 0;   // safety clamp
      gload_lds16(W + (size_t)(n0 + wrow) * K + k0 + kc * 8, &Ws[buf][sl * 512]);
    }
  };

  stage(0, k_beg);
  int cur = 0;
  for (int ki = 0; ki < nk; ki++) {
    __syncthreads();                       // stage(cur) complete; prior reads done
    if (ki + 1 < nk) stage(cur ^ 1, k_beg + ((ki + 1) << 5));   // async prefetch
    half8 af[4], wf[NT];
#pragma unroll
    for (int i = 0; i < 4; i++)
      af[i] = *(const half8*)&As[cur][(wm + i * 16 + fr) * 32 + kc8 * 8];
#pragma unroll
    for (int j = 0; j < NT; j++)
      wf[j] = *(const half8*)&Ws[cur][(wn + j * 16 + fr) * 32 + kc8 * 8];
#pragma unroll
    for (int i = 0; i < 4; i++)
#pragma unroll
      for (int j = 0; j < NT; j++)
        acc[i][j] = __builtin_amdgcn_mfma_f32_16x16x32_f16(af[i], wf[j], acc[i][j], 0, 0, 0);
    cur ^= 1;
  }

  // epilogue: C/D layout col = lane&15, row = (lane>>4)*4 + reg
  const int col = lane & 15, rowq = lane >> 4;
#pragma unroll
  for (int i = 0; i < 4; i++) {
#pragma unroll
    for (int j = 0; j < NT; j++) {
      const int n = n0 + wn + j * 16 + col;
      if (n < N) {
#pragma unroll
        for (int r = 0; r < 4; r++) {
          const int m = m0 + wm + i * 16 + rowq * 4 + r;
          float v = acc[i][j][r];
          if (EPI == 0) {
            if (n < DI) ((_Float16*)Cv )[(size_t)m * DI + n]      = (_Float16)v;
            else        ((_Float16*)C2v)[(size_t)m * DI + n - DI] = (_Float16)v;
          } else if (EPI == 1) {
            v += extra[n];
            v = (v > 20.f) ? v : log1pf(expf(v));   // softplus
            ((float*)Cv)[(size_t)m * ldc + n] = v;
          } else if (EPI == 4) {
            ((float*)Cv)[((size_t)blockIdx.z * M + m) * ldc + n] = v;
          }
        }
      }
    }
  }
}

// ---------------------------------------------------------------------------
// x_proj partial reduce: x_dbl = sum_z part[z], also emit dtr f16 (cols<64).
// ---------------------------------------------------------------------------
__global__ __launch_bounds__(256) void xproj_reduce(
    const float* __restrict__ part,      // [16][MR][XDBL]
    float* __restrict__ x_dbl, _Float16* __restrict__ dtr) {
  const int idx = blockIdx.x * 256 + threadIdx.x;   // MR*XDBL = 196608
  const int m = idx / XDBL, c = idx - m * XDBL;
  float s = 0.f;
#pragma unroll
  for (int z = 0; z < 16; z++) s += part[(size_t)z * (MR * XDBL) + idx];
  x_dbl[idx] = s;
  if (c < DTR) dtr[m * DTR + c] = (_Float16)s;
}

// ---------------------------------------------------------------------------
// out_proj partial reduce + residual: out = x + p0 + p1.
// ---------------------------------------------------------------------------
__global__ __launch_bounds__(256) void out_reduce(
    const float* __restrict__ x, const float* __restrict__ part,  // [2][MR][DM]
    float* __restrict__ out) {
  const int i = blockIdx.x * 256 + threadIdx.x;   // MR*DM/4 = 524288
  float4 a  = ((const float4*)x)[i];
  float4 p0 = ((const float4*)part)[i];
  float4 p1 = ((const float4*)(part + (size_t)MR * DM))[i];
  float4 r = make_float4(a.x + p0.x + p1.x, a.y + p0.y + p1.y,
                         a.z + p0.z + p1.z, a.w + p0.w + p1.w);
  ((float4*)out)[i] = r;
}

// ---------------------------------------------------------------------------
// Depthwise causal conv1d (width 4) + bias + SiLU, 8 channels per thread.
// ---------------------------------------------------------------------------
__global__ __launch_bounds__(256) void conv_silu_kernel(
    const _Float16* __restrict__ xin, const float* __restrict__ cw,
    const float* __restrict__ cb, _Float16* __restrict__ xc) {
  const int idx = blockIdx.x * 256 + threadIdx.x;   // 0 .. MR*DI/8-1
  const int d8 = idx & (DI / 8 - 1);
  const int ml = idx >> 8;
  const int l  = ml & (LL - 1);
  const int d0 = d8 * 8;
  half8 xr[4];
  const half8 zero = {0, 0, 0, 0, 0, 0, 0, 0};
#pragma unroll
  for (int k = 0; k < 4; k++) {
    const int lp = l - 3 + k;
    xr[k] = (lp >= 0) ? *(const half8*)&xin[(size_t)(ml - 3 + k) * DI + d0] : zero;
  }
  half8 o;
#pragma unroll
  for (int j = 0; j < 8; j++) {
    float acc = cb[d0 + j];
#pragma unroll
    for (int k = 0; k < 4; k++)
      acc += (float)xr[k][j] * cw[(d0 + j) * 4 + k];
    o[j] = (_Float16)(acc / (1.f + __expf(-acc)));
  }
  *(half8*)&xc[(size_t)ml * DI + d0] = o;
}

// ---------------------------------------------------------------------------
// Load per-channel A row; detect S4D-real init a[s] == -(s+1) (uniform).
// ---------------------------------------------------------------------------
__device__ __forceinline__ bool load_a(const float* __restrict__ A_log, int d,
                                       float* a) {
  const float4* Ap = (const float4*)(A_log + (size_t)d * DS);
  bool fast = true;
#pragma unroll
  for (int i = 0; i < 4; i++) {
    float4 v = Ap[i];
    a[4 * i + 0] = -__expf(v.x); a[4 * i + 1] = -__expf(v.y);
    a[4 * i + 2] = -__expf(v.z); a[4 * i + 3] = -__expf(v.w);
  }
#pragma unroll
  for (int s = 0; s < DS; s++)
    fast = fast && (fabsf(a[s] + (float)(s + 1)) < 1e-4f);
  return fast;
}

// ---------------------------------------------------------------------------
// Chunked selective scan, phase 1: per-(b,chunk) local scan with h=0 init.
// Fast path: exp(dt*a[s]) = r^(s+1), r = exp(-dt)  (1 exp + 15 mul vs 16 exp).
// ---------------------------------------------------------------------------
__global__ __launch_bounds__(256) void scan_phase1(
    const _Float16* __restrict__ xc,  // x_conv (MR x DI) f16
    const float* __restrict__ xdbl,   // (MR x 96)
    const float* __restrict__ dtm,    // dt after softplus (MR x DI) f32
    const float* __restrict__ A_log,
    float* __restrict__ HE,           // (NB*NC*DS) x DI
    float* __restrict__ SA) {         // (NB*NC) x DI
  __shared__ float Bs[CL][DS];
  const int bi = blockIdx.x;
  const int dblk = bi & 7;
  const int c = (bi >> 3) & (NC - 1);
  const int b = bi >> 8;
  const int t = threadIdx.x;
  const int d = dblk * 256 + t;
  const int mlbase = b * LL + c * CL;

  for (int i = t; i < CL * DS; i += 256) {
    int tt = i >> 4, s = i & 15;
    Bs[tt][s] = xdbl[(size_t)(mlbase + tt) * XDBL + DTR + s];
  }

  float a[DS];
  const bool fast = load_a(A_log, d, a);
  float h[DS];
#pragma unroll
  for (int s = 0; s < DS; s++) h[s] = 0.f;
  float S = 0.f;
  __syncthreads();

  if (fast) {
    for (int tt = 0; tt < CL; tt++) {
      const size_t ml = mlbase + tt;
      const float dtv = dtm[ml * DI + d];
      const float u   = (float)xc[ml * DI + d];
      const float du  = dtv * u;
      S += dtv;
      const float r = __expf(-dtv);
      float P = 1.f;
#pragma unroll
      for (int s = 0; s < DS; s++) {
        P *= r;
        h[s] = P * h[s] + du * Bs[tt][s];
      }
    }
  } else {
    for (int tt = 0; tt < CL; tt++) {
      const size_t ml = mlbase + tt;
      const float dtv = dtm[ml * DI + d];
      const float u   = (float)xc[ml * DI + d];
      const float du  = dtv * u;
      S += dtv;
#pragma unroll
      for (int s = 0; s < DS; s++)
        h[s] = __expf(dtv * a[s]) * h[s] + du * Bs[tt][s];
    }
  }
  const size_t base = ((size_t)(b * NC + c) * DS) * DI + d;
#pragma unroll
  for (int s = 0; s < DS; s++) HE[base + (size_t)s * DI] = h[s];
  SA[(size_t)(b * NC + c) * DI + d] = S;
}

// ---------------------------------------------------------------------------
// Phase 2: sequential combine over chunk aggregates; HE becomes carry-in.
// ---------------------------------------------------------------------------
__global__ __launch_bounds__(256) void scan_phase2(
    const float* __restrict__ A_log,
    const float* __restrict__ SA,
    float* __restrict__ HE) {
  const int idx = blockIdx.x * 256 + threadIdx.x;  // NB*DS*DI
  const int d = idx & (DI - 1);
  const int s = (idx >> 11) & (DS - 1);
  const int b = idx >> 15;
  const float a = -__expf(A_log[(size_t)d * DS + s]);
  float Hc = 0.f;
  for (int c = 0; c < NC; c++) {
    const size_t o = ((size_t)(b * NC + c) * DS + s) * DI + d;
    const float he = HE[o];
    const float P = __expf(a * SA[(size_t)(b * NC + c) * DI + d]);
    HE[o] = Hc;
    Hc = P * Hc + he;
  }
}

// ---------------------------------------------------------------------------
// Phase 3: re-run chunks with carry-in; fuse y = (sum_s h*C + u*D)*silu(z).
// ---------------------------------------------------------------------------
__global__ __launch_bounds__(256) void scan_phase3(
    const _Float16* __restrict__ xc,
    const float* __restrict__ xdbl,
    const float* __restrict__ dtm,
    const _Float16* __restrict__ zbuf,  // z (MR x DI) f16
    const float* __restrict__ A_log,
    const float* __restrict__ Dvec,
    const float* __restrict__ HE,
    _Float16* __restrict__ y) {         // (MR x DI) f16
  __shared__ float Bs[CL][DS];
  __shared__ float Cs[CL][DS];
  const int bi = blockIdx.x;
  const int dblk = bi & 7;
  const int c = (bi >> 3) & (NC - 1);
  const int b = bi >> 8;
  const int t = threadIdx.x;
  const int d = dblk * 256 + t;
  const int mlbase = b * LL + c * CL;

  for (int i = t; i < CL * DS; i += 256) {
    int tt = i >> 4, s = i & 15;
    const size_t ro = (size_t)(mlbase + tt) * XDBL + DTR + s;
    Bs[tt][s] = xdbl[ro];
    Cs[tt][s] = xdbl[ro + DS];
  }

  float a[DS];
  const bool fast = load_a(A_log, d, a);
  float h[DS];
  const size_t base = ((size_t)(b * NC + c) * DS) * DI + d;
#pragma unroll
  for (int s = 0; s < DS; s++) h[s] = HE[base + (size_t)s * DI];
  const float Dv = Dvec[d];
  __syncthreads();

  if (fast) {
    for (int tt = 0; tt < CL; tt++) {
      const size_t ml = mlbase + tt;
      const float dtv = dtm[ml * DI + d];
      const float u   = (float)xc[ml * DI + d];
      const float du  = dtv * u;
      const float r = __expf(-dtv);
      float P = 1.f, p = 0.f;
#pragma unroll
      for (int s = 0; s < DS; s++) {
        P *= r;
        h[s] = P * h[s] + du * Bs[tt][s];
        p += h[s] * Cs[tt][s];
      }
      const float zv = (float)zbuf[ml * DI + d];
      const float sil = zv / (1.f + __expf(-zv));
      y[ml * DI + d] = (_Float16)((p + u * Dv) * sil);
    }
  } else {
    for (int tt = 0; tt < CL; tt++) {
      const size_t ml = mlbase + tt;
      const float dtv = dtm[ml * DI + d];
      const float u   = (float)xc[ml * DI + d];
      const float du  = dtv * u;
      float p = 0.f;
#pragma unroll
      for (int s = 0; s < DS; s++) {
        h[s] = __expf(dtv * a[s]) * h[s] + du * Bs[tt][s];
        p += h[s] * Cs[tt][s];
      }
      const float zv = (float)zbuf[ml * DI + d];
      const float sil = zv / (1.f + __expf(-zv));
      y[ml * DI + d] = (_Float16)((p + u * Dv) * sil);
    }
  }
}

// ---------------------------------------------------------------------------
// Launch
// ---------------------------------------------------------------------------
extern "C" void kernel_launch(void* const* d_in, const int* in_sizes, int n_in,
                              void* d_out, int out_size, void* d_ws, size_t ws_size,
                              hipStream_t stream) {
  const float* x         = (const float*)d_in[0];
  const float* ln_w      = (const float*)d_in[1];
  const float* ln_b      = (const float*)d_in[2];
  const float* in_proj_w = (const float*)d_in[3];   // (4096, 1024)
  const float* conv_w    = (const float*)d_in[4];   // (2048, 1, 4)
  const float* conv_b    = (const float*)d_in[5];
  const float* x_proj_w  = (const float*)d_in[6];   // (96, 2048)
  const float* dt_proj_w = (const float*)d_in[7];   // (2048, 64)
  const float* dt_proj_b = (const float*)d_in[8];
  const float* A_log     = (const float*)d_in[9];   // (2048, 16)
  const float* Dvec      = (const float*)d_in[10];
  const float* out_proj_w= (const float*)d_in[11];  // (1024, 2048)
  float* out = (float*)d_out;

  // workspace layout (bytes; total ~82 MB)
  char* ws = (char*)d_ws;
  _Float16* h_h     = (_Float16*)ws;                 //  4 MB (MR*DM) — dead after in_proj
  _Float16* xin_h   = (_Float16*)(ws + 4194304);     //  8 MB — dead after conv
  _Float16* y_h     = xin_h;                         //  aliases xin
  _Float16* z_h     = (_Float16*)(ws + 12582912);    //  8 MB
  _Float16* xc_h    = (_Float16*)(ws + 20971520);    //  8 MB
  float*    dtb     = (float*)   (ws + 29360128);    // 16 MB (MR*DI f32) — dead after p3
  float*    out_part= dtb;                           //  16 MB, aliases dtb (step 7)
  float*    x_dbl   = (float*)   (ws + 46137344);    //  0.75 MB
  float*    SA      = (float*)   (ws + 46923776);    //  0.5 MB
  _Float16* dtr_h   = (_Float16*)(ws + 47448064);    //  0.25 MB
  float*    HE      = (float*)   (ws + 47710208);    //  8 MB
  _Float16* w_in_h  = (_Float16*)(ws + 56098816);    //  8 MB
  _Float16* w_out_h = (_Float16*)(ws + 64487424);    //  4 MB
  _Float16* w_xp_h  = (_Float16*)(ws + 68681728);    //  0.375 MB
  _Float16* w_dt_h  = (_Float16*)(ws + 69074944);    //  0.25 MB
  float*    xp_part = (float*)   (ws + 69337088);    // 12.6 MB (16 x MR x 96 f32)

  // 0+1. fused: layernorm + weight f2h
  front_kernel<<<MR + 6464, 256, 0, stream>>>(
      x, ln_w, ln_b, in_proj_w, out_proj_w, x_proj_w, dt_proj_w,
      h_h, w_in_h, w_out_h, w_xp_h, w_dt_h);

  // 2. in_proj: N=4096, tile 128x64, dbuf pipeline -> 1024 blocks
  gemm_mfma<0, 64><<<dim3(2 * DI / 64, MR / 128, 1), 256, 0, stream>>>(
      h_h, w_in_h, xin_h, z_h, nullptr, 0, MR, 2 * DI, DM, DM);

  // 3. conv + silu -> xc_h (f16), 8 channels/thread
  conv_silu_kernel<<<(MR * DI / 8) / 256, 256, 0, stream>>>(xin_h, conv_w, conv_b, xc_h);

  // 4. x_proj: tile 128x96, split-K 16 -> streaming partials (no atomics)
  gemm_mfma<4, 96><<<dim3(1, MR / 128, 16), 256, 0, stream>>>(
      xc_h, w_xp_h, xp_part, nullptr, nullptr, XDBL, MR, XDBL, DI, DI / 16);
  xproj_reduce<<<(MR * XDBL) / 256, 256, 0, stream>>>(xp_part, x_dbl, dtr_h);

  // 5. dt: MFMA + softplus (tile 128x64), K=64
  gemm_mfma<1, 64><<<dim3(DI / 64, MR / 128, 1), 256, 0, stream>>>(
      dtr_h, w_dt_h, dtb, nullptr, dt_proj_b, DI, MR, DI, DTR, DTR);

  // 6. chunked selective scan
  scan_phase1<<<NB * NC * (DI / 256), 256, 0, stream>>>(
      xc_h, x_dbl, dtb, A_log, HE, SA);
  scan_phase2<<<(NB * DS * DI) / 256, 256, 0, stream>>>(A_log, SA, HE);
  scan_phase3<<<NB * NC * (DI / 256), 256, 0, stream>>>(
      xc_h, x_dbl, dtb, z_h, A_log, Dvec, HE, y_h);

  // 7. out_proj: tile 128x64, split-K 2 -> partials (aliases dead dtb), then
  //    out = x + p0 + p1
  gemm_mfma<4, 64><<<dim3(DM / 64, MR / 128, 2), 256, 0, stream>>>(
      y_h, w_out_h, out_part, nullptr, nullptr, DM, MR, DM, DI, DI / 2);
  out_reduce<<<(MR * DM / 4) / 256, 256, 0, stream>>>(x, out_part, out);
}